// Round 6
// baseline (408.715 us; speedup 1.0000x reference)
//
#include <hip/hip_runtime.h>
#include <math.h>

typedef __attribute__((ext_vector_type(8))) short bf16x8;
typedef __attribute__((ext_vector_type(8))) unsigned short u16x8;
typedef __attribute__((ext_vector_type(4))) float f32x4;

__device__ __forceinline__ float lrelu(float x) { return x > 0.f ? x : 0.2f * x; }

__device__ __forceinline__ unsigned short f2bf(float f) {
  unsigned int u = __float_as_uint(f);
  unsigned int r = (u + 0x7FFFu + ((u >> 16) & 1u)) >> 16;   // RNE
  return (unsigned short)r;
}
__device__ __forceinline__ float bf2f(unsigned short h) {
  return __uint_as_float(((unsigned int)h) << 16);
}

// swizzled LDS offset (in shorts) for [rows][64]bf16 tile: 16B chunk c16 of row
__device__ __forceinline__ int swz(int row, int c16) {
  return (row * 8 + (c16 ^ (row & 7))) * 8;
}

// ---------------- W1 split+transpose: [256][256] -> hi/lo [n][k] ----------------
__global__ __launch_bounds__(256) void k_splitW(const float* __restrict__ W,
    unsigned short* __restrict__ Wth, unsigned short* __restrict__ Wtl)
{
  int nn = blockIdx.x;      // 256
  int k = threadIdx.x;      // 256
  float v = W[k * 256 + nn];
  unsigned short h = f2bf(v);
  unsigned short l = f2bf(v - bf2f(h));
  Wth[nn * 256 + k] = h;
  Wtl[nn * 256 + k] = l;
}

// ---------------- W2 split+transpose: [256][32] -> hi/lo [32][256] ----------------
__global__ __launch_bounds__(256) void k_splitW2(const float* __restrict__ W,
    unsigned short* __restrict__ Wth, unsigned short* __restrict__ Wtl)
{
  int nn = blockIdx.x;      // 32
  int k = threadIdx.x;      // 256
  float v = W[k * 32 + nn];
  unsigned short h = f2bf(v);
  unsigned short l = f2bf(v - bf2f(h));
  Wth[nn * 256 + k] = h;
  Wtl[nn * 256 + k] = l;
}

// ---------------- GEMM1: fused x-split + split-bf16 MFMA + fused as1/ad1 epilogue ----------------
// BM=128, BN=256(full), BK=64; 8 waves (2x4). A: fp32 x loaded, split hi/lo in-register,
// staged to swizzled LDS. B: pre-split W1^T direct from L2. Epilogue: h1b head-major
// [8][n][32] bf16 + as1h/ad1h [8][n] f32 (per-head dot with a_src1/a_dst1).
__global__ __launch_bounds__(512, 4) void k_gemm1(
    const float* __restrict__ X,
    const unsigned short* __restrict__ Bth, const unsigned short* __restrict__ Btl,
    const float* __restrict__ a_src, const float* __restrict__ a_dst,
    unsigned short* __restrict__ h1b, float* __restrict__ as1h, float* __restrict__ ad1h,
    int M)
{
  __shared__ __align__(16) unsigned short Ah[128 * 64];
  __shared__ __align__(16) unsigned short Al[128 * 64];
  const int t = threadIdx.x;
  const int lane = t & 63;
  const int w = t >> 6;
  const int wm = w >> 2, wn = w & 3;
  const int lrow = lane & 15, lkb = lane >> 4;
  const int brow = blockIdx.x * 128;

  f32x4 acc[4][4];
#pragma unroll
  for (int i = 0; i < 4; ++i)
#pragma unroll
    for (int j = 0; j < 4; ++j) acc[i][j] = (f32x4){0.f, 0.f, 0.f, 0.f};

  for (int kt = 0; kt < 4; ++kt) {
    const int k0 = kt * 64;
    // stage A tile: 128 rows x 64 cols fp32 -> bf16 hi/lo, swizzled LDS
#pragma unroll
    for (int r = 0; r < 4; ++r) {
      int id = r * 512 + t;
      int m = id >> 4, cq = id & 15;          // quad of 4 floats
      int gm = brow + m;
      float4 v = make_float4(0.f, 0.f, 0.f, 0.f);
      if (gm < M) v = *(const float4*)&X[(size_t)gm * 256 + k0 + cq * 4];
      unsigned short h0 = f2bf(v.x), h1 = f2bf(v.y), h2 = f2bf(v.z), h3 = f2bf(v.w);
      unsigned short l0 = f2bf(v.x - bf2f(h0)), l1 = f2bf(v.y - bf2f(h1));
      unsigned short l2 = f2bf(v.z - bf2f(h2)), l3 = f2bf(v.w - bf2f(h3));
      int off = swz(m, cq >> 1) + (cq & 1) * 4;
      *(uint2*)&Ah[off] = make_uint2((unsigned)h0 | ((unsigned)h1 << 16),
                                     (unsigned)h2 | ((unsigned)h3 << 16));
      *(uint2*)&Al[off] = make_uint2((unsigned)l0 | ((unsigned)l1 << 16),
                                     (unsigned)l2 | ((unsigned)l3 << 16));
    }
    __syncthreads();
#pragma unroll
    for (int kk = 0; kk < 2; ++kk) {
      bf16x8 bh[4], bl[4];
#pragma unroll
      for (int j = 0; j < 4; ++j) {
        size_t g = (size_t)(wn * 64 + j * 16 + lrow) * 256 + k0 + kk * 32 + lkb * 8;
        bh[j] = *(const bf16x8*)&Bth[g];
        bl[j] = *(const bf16x8*)&Btl[g];
      }
#pragma unroll
      for (int i = 0; i < 4; ++i) {
        int row = wm * 64 + i * 16 + lrow;
        int lo = swz(row, kk * 4 + lkb);
        bf16x8 ah = *(const bf16x8*)&Ah[lo];
        bf16x8 al = *(const bf16x8*)&Al[lo];
#pragma unroll
        for (int j = 0; j < 4; ++j) {
          acc[i][j] = __builtin_amdgcn_mfma_f32_16x16x32_bf16(ah, bh[j], acc[i][j], 0, 0, 0);
          acc[i][j] = __builtin_amdgcn_mfma_f32_16x16x32_bf16(ah, bl[j], acc[i][j], 0, 0, 0);
          acc[i][j] = __builtin_amdgcn_mfma_f32_16x16x32_bf16(al, bh[j], acc[i][j], 0, 0, 0);
        }
      }
    }
    __syncthreads();
  }

  // per-lane a_src/a_dst values for the 4 j-frags (head 2wn + (j>>1), col (j&1)*16 + c15)
  const int c15 = lane & 15, q = lane >> 4;
  float asv[4], adv[4];
#pragma unroll
  for (int j = 0; j < 4; ++j) {
    int idx = (2 * wn + (j >> 1)) * 32 + (j & 1) * 16 + c15;
    asv[j] = a_src[idx];
    adv[j] = a_dst[idx];
  }

  const size_t sn = (size_t)M;
#pragma unroll
  for (int i = 0; i < 4; ++i) {
#pragma unroll
    for (int r = 0; r < 4; ++r) {
      int gm = brow + wm * 64 + i * 16 + q * 4 + r;
      // head-major h1b store
#pragma unroll
      for (int j = 0; j < 4; ++j) {
        if (gm < M) {
          int hd = 2 * wn + (j >> 1);
          h1b[(size_t)hd * sn * 32 + (size_t)gm * 32 + (j & 1) * 16 + c15] = f2bf(acc[i][j][r]);
        }
      }
      // fused as1/ad1: reduce over 16 lanes (c15)
      float pS0 = acc[i][0][r] * asv[0] + acc[i][1][r] * asv[1];
      float pS1 = acc[i][2][r] * asv[2] + acc[i][3][r] * asv[3];
      float pD0 = acc[i][0][r] * adv[0] + acc[i][1][r] * adv[1];
      float pD1 = acc[i][2][r] * adv[2] + acc[i][3][r] * adv[3];
#pragma unroll
      for (int off = 1; off < 16; off <<= 1) {
        pS0 += __shfl_xor(pS0, off);
        pS1 += __shfl_xor(pS1, off);
        pD0 += __shfl_xor(pD0, off);
        pD1 += __shfl_xor(pD1, off);
      }
      if (c15 == 0 && gm < M) {
        as1h[(size_t)(2 * wn) * sn + gm] = pS0;
        as1h[(size_t)(2 * wn + 1) * sn + gm] = pS1;
        ad1h[(size_t)(2 * wn) * sn + gm] = pD0;
        ad1h[(size_t)(2 * wn + 1) * sn + gm] = pD1;
      }
    }
  }
}

// ---------------- GEMM2: h2b = bf16( out1e @ W2 ), A bf16, W2 split (2-product) ----------------
__global__ __launch_bounds__(512, 4) void k_gemm2(
    const unsigned short* __restrict__ Ae,
    const unsigned short* __restrict__ Bth, const unsigned short* __restrict__ Btl,
    unsigned short* __restrict__ Cb, int M)
{
  __shared__ __align__(16) unsigned short As[256 * 64];
  const int t = threadIdx.x;
  const int lane = t & 63;
  const int w = t >> 6;
  const int lrow = lane & 15, lkb = lane >> 4;
  const int brow = blockIdx.x * 256;

  f32x4 acc[2][2];
#pragma unroll
  for (int i = 0; i < 2; ++i)
#pragma unroll
    for (int j = 0; j < 2; ++j) acc[i][j] = (f32x4){0.f, 0.f, 0.f, 0.f};

  for (int kt = 0; kt < 4; ++kt) {
    const int k0 = kt * 64;
#pragma unroll
    for (int r = 0; r < 4; ++r) {
      int id = r * 512 + t;
      int m = id >> 3, c = id & 7;
      size_t g = (size_t)(brow + m) * 256 + k0 + c * 8;
      *(u16x8*)&As[swz(m, c)] = *(const u16x8*)&Ae[g];
    }
    __syncthreads();
#pragma unroll
    for (int kk = 0; kk < 2; ++kk) {
      bf16x8 bh[2], bl[2];
#pragma unroll
      for (int j = 0; j < 2; ++j) {
        size_t g = (size_t)(j * 16 + lrow) * 256 + k0 + kk * 32 + lkb * 8;
        bh[j] = *(const bf16x8*)&Bth[g];
        bl[j] = *(const bf16x8*)&Btl[g];
      }
#pragma unroll
      for (int i = 0; i < 2; ++i) {
        int row = w * 32 + i * 16 + lrow;
        bf16x8 a = *(const bf16x8*)&As[swz(row, kk * 4 + lkb)];
#pragma unroll
        for (int j = 0; j < 2; ++j) {
          acc[i][j] = __builtin_amdgcn_mfma_f32_16x16x32_bf16(a, bh[j], acc[i][j], 0, 0, 0);
          acc[i][j] = __builtin_amdgcn_mfma_f32_16x16x32_bf16(a, bl[j], acc[i][j], 0, 0, 0);
        }
      }
    }
    __syncthreads();
  }

#pragma unroll
  for (int i = 0; i < 2; ++i) {
    int mbase = brow + w * 32 + i * 16 + (lane >> 4) * 4;
#pragma unroll
    for (int j = 0; j < 2; ++j) {
      int nc = j * 16 + (lane & 15);
#pragma unroll
      for (int r = 0; r < 4; ++r) {
        int gm = mbase + r;
        if (gm < M) Cb[(size_t)gm * 32 + nc] = f2bf(acc[i][j][r]);
      }
    }
  }
}

// ---------------- per-node attention-score precompute, layer 2 (bf16 h2) ----------------
__global__ __launch_bounds__(256) void k_srcdst2(const unsigned short* __restrict__ h2b,
    const float* __restrict__ a_src, const float* __restrict__ a_dst,
    float* __restrict__ as2, float* __restrict__ ad2, int n)
{
  int node = blockIdx.x * 4 + (threadIdx.x >> 6);
  if (node >= n) return;
  int lane = threadIdx.x & 63;
  if (lane < 32) {
    float hv = bf2f(h2b[(size_t)node * 32 + lane]);
    float ps = hv * a_src[lane];
    float pd = hv * a_dst[lane];
#pragma unroll
    for (int off = 1; off < 32; off <<= 1) {
      ps += __shfl_xor(ps, off);
      pd += __shfl_xor(pd, off);
    }
    if (lane == 0) { as2[node] = ps; ad2[node] = pd; }
  }
}

// ---------------- CSR build ----------------
__global__ void k_deg(const int* __restrict__ ei, int* __restrict__ deg, int E, int etot)
{
  int e = blockIdx.x * blockDim.x + threadIdx.x;
  if (e >= etot) return;
  int dst = (e < E) ? ei[E + e] : (e - E);
  atomicAdd(&deg[dst], 1);
}

__global__ void k_scan1(const int* __restrict__ deg, int* __restrict__ rowptr,
                        int* __restrict__ bsums, int n)
{
  __shared__ int sm[2][1024];
  int t = threadIdx.x, b = blockIdx.x;
  int i = b * 1024 + t;
  int v = (i < n) ? deg[i] : 0;
  sm[0][t] = v;
  __syncthreads();
  int pb = 0;
  for (int off = 1; off < 1024; off <<= 1) {
    int x = sm[pb][t];
    if (t >= off) x += sm[pb][t - off];
    sm[pb ^ 1][t] = x;
    pb ^= 1;
    __syncthreads();
  }
  if (i < n) rowptr[i] = sm[pb][t] - v;
  if (t == 1023) bsums[b] = sm[pb][1023];
}

__global__ void k_scan2(int* bsums, int nb)
{
  if (threadIdx.x == 0 && blockIdx.x == 0) {
    int run = 0;
    for (int b = 0; b < nb; ++b) { int t = bsums[b]; bsums[b] = run; run += t; }
  }
}

__global__ void k_scan3(int* __restrict__ rowptr, const int* __restrict__ bsums, int n, int etot)
{
  int i = blockIdx.x * blockDim.x + threadIdx.x;
  if (i < n) rowptr[i] += bsums[i >> 10];
  if (i == 0) rowptr[n] = etot;
}

__global__ void k_fill(const int* __restrict__ ei, const int* __restrict__ rowptr,
                       int* __restrict__ fillc, int* __restrict__ csrsrc, int E, int etot)
{
  int e = blockIdx.x * blockDim.x + threadIdx.x;
  if (e >= etot) return;
  int src, dst;
  if (e < E) { src = ei[e]; dst = ei[E + e]; }
  else { src = dst = e - E; }
  int pos = rowptr[dst] + atomicAdd(&fillc[dst], 1);
  csrsrc[pos] = src;
}

// ---------------- layer-1 aggregation: head-sliced for XCD L2 residency ----------------
// blockIdx.x = chunk*8 + head; wave per (node, head); single fused pass
// (unnormalized exp-weighted sum + running denominator; scale at end).
__global__ __launch_bounds__(256) void k_agg1(const unsigned short* __restrict__ h1b,
    const float* __restrict__ as1h, const float* __restrict__ ad1h,
    const int* __restrict__ rowptr, const int* __restrict__ csrsrc,
    const float* __restrict__ b1, unsigned short* __restrict__ out1e, int n)
{
  __shared__ float exps[4][64];
  __shared__ int   srcs[4][64];

  const int wid = threadIdx.x >> 6;
  const int lane = threadIdx.x & 63;
  const int hd = blockIdx.x & 7;           // low bits -> XCD round-robin
  const int node = (blockIdx.x >> 3) * 4 + wid;
  if (node >= n) return;

  const int r0 = rowptr[node];
  const int deg = rowptr[node + 1] - r0;
  const float adv = ad1h[(size_t)hd * n + node];
  const float* __restrict__ asl = as1h + (size_t)hd * n;
  const unsigned short* __restrict__ hsl = h1b + (size_t)hd * n * 32;

  const int col = lane & 31, es = lane >> 5;
  float s = 0.f, acc = 0.f;

  for (int c0 = 0; c0 < deg; c0 += 64) {
    int k = c0 + lane;
    if (k < deg) {
      int src = csrsrc[r0 + k];
      float e = fminf(lrelu(asl[src] + adv), 60.f);
      float ex = __expf(e);
      s += ex;
      exps[wid][lane] = ex;
      srcs[wid][lane] = src;
    }
    int clen = (deg - c0 < 64) ? (deg - c0) : 64;
#pragma unroll 4
    for (int j = es; j < clen; j += 2) {
      float a = exps[wid][j];
      int src = srcs[wid][j];
      acc = fmaf(a, bf2f(hsl[(size_t)src * 32 + col]), acc);
    }
  }
#pragma unroll
  for (int off = 1; off < 64; off <<= 1) s += __shfl_xor(s, off);
  acc += __shfl_xor(acc, 32);
  float inv = 1.f / (s + 1e-16f);
  if (lane < 32) {
    float o = acc * inv + b1[hd * 32 + col];
    out1e[(size_t)node * 256 + hd * 32 + col] = f2bf(o > 0.f ? o : expm1f(o));
  }
}

// ---------------- layer-2 aggregation: wave per node, no-max softmax ----------------
__global__ __launch_bounds__(256) void k_agg2(const unsigned short* __restrict__ h2b,
    const float* __restrict__ as2, const float* __restrict__ ad2,
    const int* __restrict__ rowptr, const int* __restrict__ csrsrc,
    const float* __restrict__ b2, float* __restrict__ out, int n)
{
  int node = blockIdx.x * 4 + (threadIdx.x >> 6);
  if (node >= n) return;
  int lane = threadIdx.x & 63;
  int r0 = rowptr[node];
  int deg = rowptr[node + 1] - r0;
  float adv = ad2[node];

  float s = 0.f;
  for (int k = lane; k < deg; k += 64) {
    int src = csrsrc[r0 + k];
    float e = fminf(lrelu(as2[src] + adv), 60.f);
    s += __expf(e);
  }
#pragma unroll
  for (int off = 1; off < 64; off <<= 1) s += __shfl_xor(s, off);
  float inv = 1.f / (s + 1e-16f);

  float acc = 0.f;
  int c = lane & 31;
#pragma unroll 2
  for (int k = (lane >> 5); k < deg; k += 2) {
    int src = csrsrc[r0 + k];
    float e = fminf(lrelu(as2[src] + adv), 60.f);
    float a = __expf(e) * inv;
    acc = fmaf(a, bf2f(h2b[(size_t)src * 32 + c]), acc);
  }
  acc += __shfl_xor(acc, 32);
  if (lane < 32) out[(size_t)node * 32 + c] = acc + b2[c];
}

// ---------------- host launch ----------------
extern "C" void kernel_launch(void* const* d_in, const int* in_sizes, int n_in,
                              void* d_out, int out_size, void* d_ws, size_t ws_size,
                              hipStream_t stream)
{
  const float* x      = (const float*)d_in[0];
  const int*   ei     = (const int*)d_in[1];
  const float* W1     = (const float*)d_in[3];
  const float* a_src1 = (const float*)d_in[4];
  const float* a_dst1 = (const float*)d_in[5];
  const float* b1     = (const float*)d_in[6];
  const float* W2     = (const float*)d_in[7];
  const float* a_src2 = (const float*)d_in[8];
  const float* a_dst2 = (const float*)d_in[9];
  const float* b2     = (const float*)d_in[10];
  float* out = (float*)d_out;

  const int n = in_sizes[0] / 256;            // 50000
  const int E = in_sizes[2];                  // 800000
  const int etot = E + n;
  const int Mpad = ((n + 255) / 256) * 256;   // 50176

  // workspace carve
  unsigned short* h1b   = (unsigned short*)d_ws;           // [8][n][32] bf16
  unsigned short* out1e = h1b + (size_t)n * 256;           // [Mpad][256] bf16
  unsigned short* h2b   = out1e + (size_t)Mpad * 256;      // n*32 bf16
  float* as1h = (float*)(h2b + (size_t)n * 32);            // [8][n]
  float* ad1h = as1h + (size_t)8 * n;                      // [8][n]
  float* as2v = ad1h + (size_t)8 * n;                      // n
  float* ad2v = as2v + n;                                  // n
  int* rowptr = (int*)(ad2v + n);                          // n+1
  int* degc   = rowptr + (n + 1);                          // n
  int* fillc  = degc + n;                                  // n
  int* csrsrc = fillc + n;                                 // etot
  int* bsums  = csrsrc + etot;                             // <=64
  unsigned short* wth  = (unsigned short*)(bsums + 64);    // 65536
  unsigned short* wtl  = wth + 65536;                      // 65536
  unsigned short* w2th = wtl + 65536;                      // 8192
  unsigned short* w2tl = w2th + 8192;                      // 8192

  hipMemsetAsync(degc, 0, (size_t)2 * n * sizeof(int), stream);

  // weight splits
  k_splitW<<<256, 256, 0, stream>>>(W1, wth, wtl);
  k_splitW2<<<32, 256, 0, stream>>>(W2, w2th, w2tl);

  // h1b/as1/ad1 = gemm1(x, W1) fused
  k_gemm1<<<Mpad / 128, 512, 0, stream>>>(x, wth, wtl, a_src1, a_dst1,
                                          h1b, as1h, ad1h, n);

  // CSR build
  int eb = (etot + 255) / 256;
  k_deg<<<eb, 256, 0, stream>>>(ei, degc, E, etot);
  int nblk = (n + 1023) / 1024;
  k_scan1<<<nblk, 1024, 0, stream>>>(degc, rowptr, bsums, n);
  k_scan2<<<1, 64, 0, stream>>>(bsums, nblk);
  k_scan3<<<(n + 255) / 256, 256, 0, stream>>>(rowptr, bsums, n, etot);
  k_fill<<<eb, 256, 0, stream>>>(ei, rowptr, fillc, csrsrc, E, etot);

  // layer-1 attention, head-sliced (blockIdx & 7 = head -> XCD affinity)
  int nchunk = (n + 3) / 4;
  k_agg1<<<nchunk * 8, 256, 0, stream>>>(h1b, as1h, ad1h, rowptr, csrsrc, b1, out1e, n);

  // h2b = bf16(out1e @ W2)
  k_gemm2<<<Mpad / 256, 512, 0, stream>>>(out1e, w2th, w2tl, h2b, n);

  // layer-2 attention -> output
  int nb4 = (n + 3) / 4;
  k_srcdst2<<<nb4, 256, 0, stream>>>(h2b, a_src2, a_dst2, as2v, ad2v, n);
  k_agg2<<<nb4, 256, 0, stream>>>(h2b, as2v, ad2v, rowptr, csrsrc, b2, out, n);
}

// Round 7
// 380.261 us; speedup vs baseline: 1.0748x; 1.0748x over previous
//
#include <hip/hip_runtime.h>
#include <math.h>

typedef __attribute__((ext_vector_type(8))) short bf16x8;
typedef __attribute__((ext_vector_type(8))) unsigned short u16x8;
typedef __attribute__((ext_vector_type(4))) float f32x4;

__device__ __forceinline__ float lrelu(float x) { return x > 0.f ? x : 0.2f * x; }

__device__ __forceinline__ unsigned short f2bf(float f) {
  unsigned int u = __float_as_uint(f);
  unsigned int r = (u + 0x7FFFu + ((u >> 16) & 1u)) >> 16;   // RNE
  return (unsigned short)r;
}
__device__ __forceinline__ float bf2f(unsigned short h) {
  return __uint_as_float(((unsigned int)h) << 16);
}

// swizzled LDS offset (in shorts) for [rows][64]bf16 tile: 16B chunk c16 of row
__device__ __forceinline__ int swz(int row, int c16) {
  return (row * 8 + (c16 ^ (row & 7))) * 8;
}

// ---------------- W1 split+transpose: [256][256] -> hi/lo [n][k] ----------------
__global__ __launch_bounds__(256) void k_splitW(const float* __restrict__ W,
    unsigned short* __restrict__ Wth, unsigned short* __restrict__ Wtl)
{
  int nn = blockIdx.x;      // 256
  int k = threadIdx.x;      // 256
  float v = W[k * 256 + nn];
  unsigned short h = f2bf(v);
  unsigned short l = f2bf(v - bf2f(h));
  Wth[nn * 256 + k] = h;
  Wtl[nn * 256 + k] = l;
}

// ---------------- W2 split+transpose: [256][32] -> hi/lo [32][256] ----------------
__global__ __launch_bounds__(256) void k_splitW2(const float* __restrict__ W,
    unsigned short* __restrict__ Wth, unsigned short* __restrict__ Wtl)
{
  int nn = blockIdx.x;      // 32
  int k = threadIdx.x;      // 256
  float v = W[k * 32 + nn];
  unsigned short h = f2bf(v);
  unsigned short l = f2bf(v - bf2f(h));
  Wth[nn * 256 + k] = h;
  Wtl[nn * 256 + k] = l;
}

// ---------------- GEMM1: fused x-split + split-bf16 MFMA + fused as1/ad1 epilogue ----------------
__global__ __launch_bounds__(512, 4) void k_gemm1(
    const float* __restrict__ X,
    const unsigned short* __restrict__ Bth, const unsigned short* __restrict__ Btl,
    const float* __restrict__ a_src, const float* __restrict__ a_dst,
    unsigned short* __restrict__ h1b, float* __restrict__ as1h, float* __restrict__ ad1h,
    int M)
{
  __shared__ __align__(16) unsigned short Ah[128 * 64];
  __shared__ __align__(16) unsigned short Al[128 * 64];
  const int t = threadIdx.x;
  const int lane = t & 63;
  const int w = t >> 6;
  const int wm = w >> 2, wn = w & 3;
  const int lrow = lane & 15, lkb = lane >> 4;
  const int brow = blockIdx.x * 128;

  f32x4 acc[4][4];
#pragma unroll
  for (int i = 0; i < 4; ++i)
#pragma unroll
    for (int j = 0; j < 4; ++j) acc[i][j] = (f32x4){0.f, 0.f, 0.f, 0.f};

  for (int kt = 0; kt < 4; ++kt) {
    const int k0 = kt * 64;
#pragma unroll
    for (int r = 0; r < 4; ++r) {
      int id = r * 512 + t;
      int m = id >> 4, cq = id & 15;
      int gm = brow + m;
      float4 v = make_float4(0.f, 0.f, 0.f, 0.f);
      if (gm < M) v = *(const float4*)&X[(size_t)gm * 256 + k0 + cq * 4];
      unsigned short h0 = f2bf(v.x), h1 = f2bf(v.y), h2 = f2bf(v.z), h3 = f2bf(v.w);
      unsigned short l0 = f2bf(v.x - bf2f(h0)), l1 = f2bf(v.y - bf2f(h1));
      unsigned short l2 = f2bf(v.z - bf2f(h2)), l3 = f2bf(v.w - bf2f(h3));
      int off = swz(m, cq >> 1) + (cq & 1) * 4;
      *(uint2*)&Ah[off] = make_uint2((unsigned)h0 | ((unsigned)h1 << 16),
                                     (unsigned)h2 | ((unsigned)h3 << 16));
      *(uint2*)&Al[off] = make_uint2((unsigned)l0 | ((unsigned)l1 << 16),
                                     (unsigned)l2 | ((unsigned)l3 << 16));
    }
    __syncthreads();
#pragma unroll
    for (int kk = 0; kk < 2; ++kk) {
      bf16x8 bh[4], bl[4];
#pragma unroll
      for (int j = 0; j < 4; ++j) {
        size_t g = (size_t)(wn * 64 + j * 16 + lrow) * 256 + k0 + kk * 32 + lkb * 8;
        bh[j] = *(const bf16x8*)&Bth[g];
        bl[j] = *(const bf16x8*)&Btl[g];
      }
#pragma unroll
      for (int i = 0; i < 4; ++i) {
        int row = wm * 64 + i * 16 + lrow;
        int lo = swz(row, kk * 4 + lkb);
        bf16x8 ah = *(const bf16x8*)&Ah[lo];
        bf16x8 al = *(const bf16x8*)&Al[lo];
#pragma unroll
        for (int j = 0; j < 4; ++j) {
          acc[i][j] = __builtin_amdgcn_mfma_f32_16x16x32_bf16(ah, bh[j], acc[i][j], 0, 0, 0);
          acc[i][j] = __builtin_amdgcn_mfma_f32_16x16x32_bf16(ah, bl[j], acc[i][j], 0, 0, 0);
          acc[i][j] = __builtin_amdgcn_mfma_f32_16x16x32_bf16(al, bh[j], acc[i][j], 0, 0, 0);
        }
      }
    }
    __syncthreads();
  }

  const int c15 = lane & 15, q = lane >> 4;
  float asv[4], adv[4];
#pragma unroll
  for (int j = 0; j < 4; ++j) {
    int idx = (2 * wn + (j >> 1)) * 32 + (j & 1) * 16 + c15;
    asv[j] = a_src[idx];
    adv[j] = a_dst[idx];
  }

  const size_t sn = (size_t)M;
#pragma unroll
  for (int i = 0; i < 4; ++i) {
#pragma unroll
    for (int r = 0; r < 4; ++r) {
      int gm = brow + wm * 64 + i * 16 + q * 4 + r;
#pragma unroll
      for (int j = 0; j < 4; ++j) {
        if (gm < M) {
          int hd = 2 * wn + (j >> 1);
          h1b[(size_t)hd * sn * 32 + (size_t)gm * 32 + (j & 1) * 16 + c15] = f2bf(acc[i][j][r]);
        }
      }
      float pS0 = acc[i][0][r] * asv[0] + acc[i][1][r] * asv[1];
      float pS1 = acc[i][2][r] * asv[2] + acc[i][3][r] * asv[3];
      float pD0 = acc[i][0][r] * adv[0] + acc[i][1][r] * adv[1];
      float pD1 = acc[i][2][r] * adv[2] + acc[i][3][r] * adv[3];
#pragma unroll
      for (int off = 1; off < 16; off <<= 1) {
        pS0 += __shfl_xor(pS0, off);
        pS1 += __shfl_xor(pS1, off);
        pD0 += __shfl_xor(pD0, off);
        pD1 += __shfl_xor(pD1, off);
      }
      if (c15 == 0 && gm < M) {
        as1h[(size_t)(2 * wn) * sn + gm] = pS0;
        as1h[(size_t)(2 * wn + 1) * sn + gm] = pS1;
        ad1h[(size_t)(2 * wn) * sn + gm] = pD0;
        ad1h[(size_t)(2 * wn + 1) * sn + gm] = pD1;
      }
    }
  }
}

// ---------------- GEMM2: h2b = bf16( out1e @ W2 ), A bf16, W2 split (2-product) ----------------
__global__ __launch_bounds__(512, 4) void k_gemm2(
    const unsigned short* __restrict__ Ae,
    const unsigned short* __restrict__ Bth, const unsigned short* __restrict__ Btl,
    unsigned short* __restrict__ Cb, int M)
{
  __shared__ __align__(16) unsigned short As[256 * 64];
  const int t = threadIdx.x;
  const int lane = t & 63;
  const int w = t >> 6;
  const int lrow = lane & 15, lkb = lane >> 4;
  const int brow = blockIdx.x * 256;

  f32x4 acc[2][2];
#pragma unroll
  for (int i = 0; i < 2; ++i)
#pragma unroll
    for (int j = 0; j < 2; ++j) acc[i][j] = (f32x4){0.f, 0.f, 0.f, 0.f};

  for (int kt = 0; kt < 4; ++kt) {
    const int k0 = kt * 64;
#pragma unroll
    for (int r = 0; r < 4; ++r) {
      int id = r * 512 + t;
      int m = id >> 3, c = id & 7;
      size_t g = (size_t)(brow + m) * 256 + k0 + c * 8;
      *(u16x8*)&As[swz(m, c)] = *(const u16x8*)&Ae[g];
    }
    __syncthreads();
#pragma unroll
    for (int kk = 0; kk < 2; ++kk) {
      bf16x8 bh[2], bl[2];
#pragma unroll
      for (int j = 0; j < 2; ++j) {
        size_t g = (size_t)(j * 16 + lrow) * 256 + k0 + kk * 32 + lkb * 8;
        bh[j] = *(const bf16x8*)&Bth[g];
        bl[j] = *(const bf16x8*)&Btl[g];
      }
#pragma unroll
      for (int i = 0; i < 2; ++i) {
        int row = w * 32 + i * 16 + lrow;
        bf16x8 a = *(const bf16x8*)&As[swz(row, kk * 4 + lkb)];
#pragma unroll
        for (int j = 0; j < 2; ++j) {
          acc[i][j] = __builtin_amdgcn_mfma_f32_16x16x32_bf16(a, bh[j], acc[i][j], 0, 0, 0);
          acc[i][j] = __builtin_amdgcn_mfma_f32_16x16x32_bf16(a, bl[j], acc[i][j], 0, 0, 0);
        }
      }
    }
    __syncthreads();
  }

#pragma unroll
  for (int i = 0; i < 2; ++i) {
    int mbase = brow + w * 32 + i * 16 + (lane >> 4) * 4;
#pragma unroll
    for (int j = 0; j < 2; ++j) {
      int nc = j * 16 + (lane & 15);
#pragma unroll
      for (int r = 0; r < 4; ++r) {
        int gm = mbase + r;
        if (gm < M) Cb[(size_t)gm * 32 + nc] = f2bf(acc[i][j][r]);
      }
    }
  }
}

// ---------------- per-node attention-score precompute, layer 2 (bf16 h2) ----------------
__global__ __launch_bounds__(256) void k_srcdst2(const unsigned short* __restrict__ h2b,
    const float* __restrict__ a_src, const float* __restrict__ a_dst,
    float* __restrict__ as2, float* __restrict__ ad2, int n)
{
  int node = blockIdx.x * 4 + (threadIdx.x >> 6);
  if (node >= n) return;
  int lane = threadIdx.x & 63;
  if (lane < 32) {
    float hv = bf2f(h2b[(size_t)node * 32 + lane]);
    float ps = hv * a_src[lane];
    float pd = hv * a_dst[lane];
#pragma unroll
    for (int off = 1; off < 32; off <<= 1) {
      ps += __shfl_xor(ps, off);
      pd += __shfl_xor(pd, off);
    }
    if (lane == 0) { as2[node] = ps; ad2[node] = pd; }
  }
}

// ---------------- CSR build ----------------
__global__ void k_deg(const int* __restrict__ ei, int* __restrict__ deg, int E, int etot)
{
  int e = blockIdx.x * blockDim.x + threadIdx.x;
  if (e >= etot) return;
  int dst = (e < E) ? ei[E + e] : (e - E);
  atomicAdd(&deg[dst], 1);
}

__global__ void k_scan1(const int* __restrict__ deg, int* __restrict__ rowptr,
                        int* __restrict__ bsums, int n)
{
  __shared__ int sm[2][1024];
  int t = threadIdx.x, b = blockIdx.x;
  int i = b * 1024 + t;
  int v = (i < n) ? deg[i] : 0;
  sm[0][t] = v;
  __syncthreads();
  int pb = 0;
  for (int off = 1; off < 1024; off <<= 1) {
    int x = sm[pb][t];
    if (t >= off) x += sm[pb][t - off];
    sm[pb ^ 1][t] = x;
    pb ^= 1;
    __syncthreads();
  }
  if (i < n) rowptr[i] = sm[pb][t] - v;
  if (t == 1023) bsums[b] = sm[pb][1023];
}

__global__ void k_scan2(int* bsums, int nb)
{
  if (threadIdx.x == 0 && blockIdx.x == 0) {
    int run = 0;
    for (int b = 0; b < nb; ++b) { int t = bsums[b]; bsums[b] = run; run += t; }
  }
}

__global__ void k_scan3(int* __restrict__ rowptr, const int* __restrict__ bsums, int n, int etot)
{
  int i = blockIdx.x * blockDim.x + threadIdx.x;
  if (i < n) rowptr[i] += bsums[i >> 10];
  if (i == 0) rowptr[n] = etot;
}

__global__ void k_fill(const int* __restrict__ ei, const int* __restrict__ rowptr,
                       int* __restrict__ fillc, int* __restrict__ csrsrc, int E, int etot)
{
  int e = blockIdx.x * blockDim.x + threadIdx.x;
  if (e >= etot) return;
  int src, dst;
  if (e < E) { src = ei[e]; dst = ei[E + e]; }
  else { src = dst = e - E; }
  int pos = rowptr[dst] + atomicAdd(&fillc[dst], 1);
  csrsrc[pos] = src;
}

// ---------------- layer-1 aggregation: head-sliced, 8 lanes/edge, ushort4 gathers ----------------
// blockIdx.x & 7 = head (XCD affinity); wave per (node, head); no-max softmax,
// single pass: unnormalized exp-weighted sum + denominator, scale at end.
__global__ __launch_bounds__(256) void k_agg1(const unsigned short* __restrict__ h1b,
    const float* __restrict__ as1h, const float* __restrict__ ad1h,
    const int* __restrict__ rowptr, const int* __restrict__ csrsrc,
    const float* __restrict__ b1, unsigned short* __restrict__ out1e, int n)
{
  const int wid = threadIdx.x >> 6;
  const int lane = threadIdx.x & 63;
  const int hd = blockIdx.x & 7;
  const int node = (blockIdx.x >> 3) * 4 + wid;
  if (node >= n) return;

  const int r0 = rowptr[node];
  const int deg = rowptr[node + 1] - r0;
  const float adv = ad1h[(size_t)hd * n + node];
  const float* __restrict__ asl = as1h + (size_t)hd * n;
  const unsigned short* __restrict__ hsl = h1b + (size_t)hd * n * 32;

  const int c4 = lane & 7;      // col quad: cols c4*4 .. c4*4+3
  const int es = lane >> 3;     // edge slot 0..7
  float s = 0.f;
  float ax = 0.f, ay = 0.f, az = 0.f, aw = 0.f;

  const int dfull = deg & ~7;
#pragma unroll 2
  for (int c0 = 0; c0 < dfull; c0 += 8) {
    int src = csrsrc[r0 + c0 + es];
    float e = fminf(lrelu(asl[src] + adv), 60.f);
    float ex = __expf(e);
    s += ex;
    ushort4 hv = *(const ushort4*)&hsl[(size_t)src * 32 + c4 * 4];
    ax = fmaf(ex, bf2f(hv.x), ax);
    ay = fmaf(ex, bf2f(hv.y), ay);
    az = fmaf(ex, bf2f(hv.z), az);
    aw = fmaf(ex, bf2f(hv.w), aw);
  }
  if (dfull + es < deg) {
    int src = csrsrc[r0 + dfull + es];
    float e = fminf(lrelu(asl[src] + adv), 60.f);
    float ex = __expf(e);
    s += ex;
    ushort4 hv = *(const ushort4*)&hsl[(size_t)src * 32 + c4 * 4];
    ax = fmaf(ex, bf2f(hv.x), ax);
    ay = fmaf(ex, bf2f(hv.y), ay);
    az = fmaf(ex, bf2f(hv.z), az);
    aw = fmaf(ex, bf2f(hv.w), aw);
  }
  // reduce across edge slots (lane bits 3,4,5)
#pragma unroll
  for (int off = 8; off < 64; off <<= 1) {
    s  += __shfl_xor(s, off);
    ax += __shfl_xor(ax, off);
    ay += __shfl_xor(ay, off);
    az += __shfl_xor(az, off);
    aw += __shfl_xor(aw, off);
  }
  if (es == 0) {
    float inv = 1.f / (s + 1e-16f);
    const float* bb = &b1[hd * 32 + c4 * 4];
    float ox = ax * inv + bb[0];
    float oy = ay * inv + bb[1];
    float oz = az * inv + bb[2];
    float ow = aw * inv + bb[3];
    ushort4 ob;
    ob.x = f2bf(ox > 0.f ? ox : expm1f(ox));
    ob.y = f2bf(oy > 0.f ? oy : expm1f(oy));
    ob.z = f2bf(oz > 0.f ? oz : expm1f(oz));
    ob.w = f2bf(ow > 0.f ? ow : expm1f(ow));
    *(ushort4*)&out1e[(size_t)node * 256 + hd * 32 + c4 * 4] = ob;
  }
}

// ---------------- layer-2 aggregation: 8 lanes/edge, ushort4 gathers ----------------
__global__ __launch_bounds__(256) void k_agg2(const unsigned short* __restrict__ h2b,
    const float* __restrict__ as2, const float* __restrict__ ad2,
    const int* __restrict__ rowptr, const int* __restrict__ csrsrc,
    const float* __restrict__ b2, float* __restrict__ out, int n)
{
  const int wid = threadIdx.x >> 6;
  const int lane = threadIdx.x & 63;
  const int node = blockIdx.x * 4 + wid;
  if (node >= n) return;

  const int r0 = rowptr[node];
  const int deg = rowptr[node + 1] - r0;
  const float adv = ad2[node];

  const int c4 = lane & 7;
  const int es = lane >> 3;
  float s = 0.f;
  float ax = 0.f, ay = 0.f, az = 0.f, aw = 0.f;

  const int dfull = deg & ~7;
#pragma unroll 2
  for (int c0 = 0; c0 < dfull; c0 += 8) {
    int src = csrsrc[r0 + c0 + es];
    float e = fminf(lrelu(as2[src] + adv), 60.f);
    float ex = __expf(e);
    s += ex;
    ushort4 hv = *(const ushort4*)&h2b[(size_t)src * 32 + c4 * 4];
    ax = fmaf(ex, bf2f(hv.x), ax);
    ay = fmaf(ex, bf2f(hv.y), ay);
    az = fmaf(ex, bf2f(hv.z), az);
    aw = fmaf(ex, bf2f(hv.w), aw);
  }
  if (dfull + es < deg) {
    int src = csrsrc[r0 + dfull + es];
    float e = fminf(lrelu(as2[src] + adv), 60.f);
    float ex = __expf(e);
    s += ex;
    ushort4 hv = *(const ushort4*)&h2b[(size_t)src * 32 + c4 * 4];
    ax = fmaf(ex, bf2f(hv.x), ax);
    ay = fmaf(ex, bf2f(hv.y), ay);
    az = fmaf(ex, bf2f(hv.z), az);
    aw = fmaf(ex, bf2f(hv.w), aw);
  }
#pragma unroll
  for (int off = 8; off < 64; off <<= 1) {
    s  += __shfl_xor(s, off);
    ax += __shfl_xor(ax, off);
    ay += __shfl_xor(ay, off);
    az += __shfl_xor(az, off);
    aw += __shfl_xor(aw, off);
  }
  if (es == 0) {
    float inv = 1.f / (s + 1e-16f);
    float4 o;
    o.x = ax * inv + b2[c4 * 4 + 0];
    o.y = ay * inv + b2[c4 * 4 + 1];
    o.z = az * inv + b2[c4 * 4 + 2];
    o.w = aw * inv + b2[c4 * 4 + 3];
    *(float4*)&out[(size_t)node * 32 + c4 * 4] = o;
  }
}

// ---------------- host launch ----------------
extern "C" void kernel_launch(void* const* d_in, const int* in_sizes, int n_in,
                              void* d_out, int out_size, void* d_ws, size_t ws_size,
                              hipStream_t stream)
{
  const float* x      = (const float*)d_in[0];
  const int*   ei     = (const int*)d_in[1];
  const float* W1     = (const float*)d_in[3];
  const float* a_src1 = (const float*)d_in[4];
  const float* a_dst1 = (const float*)d_in[5];
  const float* b1     = (const float*)d_in[6];
  const float* W2     = (const float*)d_in[7];
  const float* a_src2 = (const float*)d_in[8];
  const float* a_dst2 = (const float*)d_in[9];
  const float* b2     = (const float*)d_in[10];
  float* out = (float*)d_out;

  const int n = in_sizes[0] / 256;            // 50000
  const int E = in_sizes[2];                  // 800000
  const int etot = E + n;
  const int Mpad = ((n + 255) / 256) * 256;   // 50176

  // workspace carve
  unsigned short* h1b   = (unsigned short*)d_ws;           // [8][n][32] bf16
  unsigned short* out1e = h1b + (size_t)n * 256;           // [Mpad][256] bf16
  unsigned short* h2b   = out1e + (size_t)Mpad * 256;      // n*32 bf16
  float* as1h = (float*)(h2b + (size_t)n * 32);            // [8][n]
  float* ad1h = as1h + (size_t)8 * n;                      // [8][n]
  float* as2v = ad1h + (size_t)8 * n;                      // n
  float* ad2v = as2v + n;                                  // n
  int* rowptr = (int*)(ad2v + n);                          // n+1
  int* degc   = rowptr + (n + 1);                          // n
  int* fillc  = degc + n;                                  // n
  int* csrsrc = fillc + n;                                 // etot
  int* bsums  = csrsrc + etot;                             // <=64
  unsigned short* wth  = (unsigned short*)(bsums + 64);    // 65536
  unsigned short* wtl  = wth + 65536;                      // 65536
  unsigned short* w2th = wtl + 65536;                      // 8192
  unsigned short* w2tl = w2th + 8192;                      // 8192

  hipMemsetAsync(degc, 0, (size_t)2 * n * sizeof(int), stream);

  // weight splits
  k_splitW<<<256, 256, 0, stream>>>(W1, wth, wtl);
  k_splitW2<<<32, 256, 0, stream>>>(W2, w2th, w2tl);

  // h1b/as1/ad1 = gemm1(x, W1) fused
  k_gemm1<<<Mpad / 128, 512, 0, stream>>>(x, wth, wtl, a_src1, a_dst1,
                                          h1b, as1h, ad1h, n);

  // CSR build
  int eb = (etot + 255) / 256;
  k_deg<<<eb, 256, 0, stream>>>(ei, degc, E, etot);
  int nblk = (n + 1023) / 1024;
  k_scan1<<<nblk, 1024, 0, stream>>>(degc, rowptr, bsums, n);
  k_scan2<<<1, 64, 0, stream>>>(bsums, nblk);
  k_scan3<<<(n + 255) / 256, 256, 0, stream>>>(rowptr, bsums, n, etot);
  k_fill<<<eb, 256, 0, stream>>>(ei, rowptr, fillc, csrsrc, E, etot);

  // layer-1 attention, head-sliced
  int nchunk = (n + 3) / 4;
  k_agg1<<<nchunk * 8, 256, 0, stream>>>(h1b, as1h, ad1h, rowptr, csrsrc, b1, out1e, n);

  // h2b = bf16(out1e @ W2)
  k_gemm2<<<Mpad / 256, 512, 0, stream>>>(out1e, w2th, w2tl, h2b, n);

  // layer-2 attention -> output
  int nb4 = (n + 3) / 4;
  k_srcdst2<<<nb4, 256, 0, stream>>>(h2b, a_src2, a_dst2, as2v, ad2v, n);
  k_agg2<<<nb4, 256, 0, stream>>>(h2b, as2v, ad2v, rowptr, csrsrc, b2, out, n);
}

// Round 8
// 300.477 us; speedup vs baseline: 1.3602x; 1.2655x over previous
//
#include <hip/hip_runtime.h>
#include <math.h>

typedef __attribute__((ext_vector_type(8))) short bf16x8;
typedef __attribute__((ext_vector_type(8))) unsigned short u16x8;
typedef __attribute__((ext_vector_type(4))) float f32x4;

__device__ __forceinline__ float lrelu(float x) { return x > 0.f ? x : 0.2f * x; }

__device__ __forceinline__ unsigned short f2bf(float f) {
  unsigned int u = __float_as_uint(f);
  unsigned int r = (u + 0x7FFFu + ((u >> 16) & 1u)) >> 16;   // RNE
  return (unsigned short)r;
}
__device__ __forceinline__ float bf2f(unsigned short h) {
  return __uint_as_float(((unsigned int)h) << 16);
}

// swizzled LDS offset (in shorts) for [rows][64]bf16 tile: 16B chunk c16 of row
__device__ __forceinline__ int swz(int row, int c16) {
  return (row * 8 + (c16 ^ (row & 7))) * 8;
}

// ---------------- W1 split+transpose: [256][256] -> hi/lo [n][k] ----------------
__global__ __launch_bounds__(256) void k_splitW(const float* __restrict__ W,
    unsigned short* __restrict__ Wth, unsigned short* __restrict__ Wtl)
{
  int nn = blockIdx.x;      // 256
  int k = threadIdx.x;      // 256
  float v = W[k * 256 + nn];
  unsigned short h = f2bf(v);
  unsigned short l = f2bf(v - bf2f(h));
  Wth[nn * 256 + k] = h;
  Wtl[nn * 256 + k] = l;
}

// ---------------- W2 split+transpose: [256][32] -> hi/lo [32][256] ----------------
__global__ __launch_bounds__(256) void k_splitW2(const float* __restrict__ W,
    unsigned short* __restrict__ Wth, unsigned short* __restrict__ Wtl)
{
  int nn = blockIdx.x;      // 32
  int k = threadIdx.x;      // 256
  float v = W[k * 32 + nn];
  unsigned short h = f2bf(v);
  unsigned short l = f2bf(v - bf2f(h));
  Wth[nn * 256 + k] = h;
  Wtl[nn * 256 + k] = l;
}

// ---------------- GEMM1: fused x-split + split-bf16 MFMA ----------------
// BM=128, BN=256(full), BK=64; 8 waves (2x4). Epilogue: LDS-transposed coalesced
// bf16 C stores (node-major h1b [n][256]) + fused as1/ad1 ([n][8] interleaved).
__global__ __launch_bounds__(512, 4) void k_gemm1(
    const float* __restrict__ X,
    const unsigned short* __restrict__ Bth, const unsigned short* __restrict__ Btl,
    const float* __restrict__ a_src, const float* __restrict__ a_dst,
    unsigned short* __restrict__ h1b, float* __restrict__ as1, float* __restrict__ ad1,
    int M)
{
  __shared__ __align__(16) unsigned short Ah[128 * 64];
  __shared__ __align__(16) unsigned short Al[128 * 64];
  const int t = threadIdx.x;
  const int lane = t & 63;
  const int w = t >> 6;
  const int wm = w >> 2, wn = w & 3;
  const int lrow = lane & 15, lkb = lane >> 4;
  const int brow = blockIdx.x * 128;

  f32x4 acc[4][4];
#pragma unroll
  for (int i = 0; i < 4; ++i)
#pragma unroll
    for (int j = 0; j < 4; ++j) acc[i][j] = (f32x4){0.f, 0.f, 0.f, 0.f};

  for (int kt = 0; kt < 4; ++kt) {
    const int k0 = kt * 64;
#pragma unroll
    for (int r = 0; r < 4; ++r) {
      int id = r * 512 + t;
      int m = id >> 4, cq = id & 15;
      int gm = brow + m;
      float4 v = make_float4(0.f, 0.f, 0.f, 0.f);
      if (gm < M) v = *(const float4*)&X[(size_t)gm * 256 + k0 + cq * 4];
      unsigned short h0 = f2bf(v.x), h1 = f2bf(v.y), h2 = f2bf(v.z), h3 = f2bf(v.w);
      unsigned short l0 = f2bf(v.x - bf2f(h0)), l1 = f2bf(v.y - bf2f(h1));
      unsigned short l2 = f2bf(v.z - bf2f(h2)), l3 = f2bf(v.w - bf2f(h3));
      int off = swz(m, cq >> 1) + (cq & 1) * 4;
      *(uint2*)&Ah[off] = make_uint2((unsigned)h0 | ((unsigned)h1 << 16),
                                     (unsigned)h2 | ((unsigned)h3 << 16));
      *(uint2*)&Al[off] = make_uint2((unsigned)l0 | ((unsigned)l1 << 16),
                                     (unsigned)l2 | ((unsigned)l3 << 16));
    }
    __syncthreads();
#pragma unroll
    for (int kk = 0; kk < 2; ++kk) {
      bf16x8 bh[4], bl[4];
#pragma unroll
      for (int j = 0; j < 4; ++j) {
        size_t g = (size_t)(wn * 64 + j * 16 + lrow) * 256 + k0 + kk * 32 + lkb * 8;
        bh[j] = *(const bf16x8*)&Bth[g];
        bl[j] = *(const bf16x8*)&Btl[g];
      }
#pragma unroll
      for (int i = 0; i < 4; ++i) {
        int row = wm * 64 + i * 16 + lrow;
        int lo = swz(row, kk * 4 + lkb);
        bf16x8 ah = *(const bf16x8*)&Ah[lo];
        bf16x8 al = *(const bf16x8*)&Al[lo];
#pragma unroll
        for (int j = 0; j < 4; ++j) {
          acc[i][j] = __builtin_amdgcn_mfma_f32_16x16x32_bf16(ah, bh[j], acc[i][j], 0, 0, 0);
          acc[i][j] = __builtin_amdgcn_mfma_f32_16x16x32_bf16(ah, bl[j], acc[i][j], 0, 0, 0);
          acc[i][j] = __builtin_amdgcn_mfma_f32_16x16x32_bf16(al, bh[j], acc[i][j], 0, 0, 0);
        }
      }
    }
    __syncthreads();
  }

  const int c15 = lane & 15, q = lane >> 4;

  // ---- fused as1/ad1 (heads 2wn, 2wn+1), interleaved [n][8] layout ----
  float asv[4], adv[4];
#pragma unroll
  for (int j = 0; j < 4; ++j) {
    int idx = (2 * wn + (j >> 1)) * 32 + (j & 1) * 16 + c15;
    asv[j] = a_src[idx];
    adv[j] = a_dst[idx];
  }
#pragma unroll
  for (int i = 0; i < 4; ++i) {
#pragma unroll
    for (int r = 0; r < 4; ++r) {
      int gm = brow + wm * 64 + i * 16 + q * 4 + r;
      float pS0 = acc[i][0][r] * asv[0] + acc[i][1][r] * asv[1];
      float pS1 = acc[i][2][r] * asv[2] + acc[i][3][r] * asv[3];
      float pD0 = acc[i][0][r] * adv[0] + acc[i][1][r] * adv[1];
      float pD1 = acc[i][2][r] * adv[2] + acc[i][3][r] * adv[3];
#pragma unroll
      for (int off = 1; off < 16; off <<= 1) {
        pS0 += __shfl_xor(pS0, off);
        pS1 += __shfl_xor(pS1, off);
        pD0 += __shfl_xor(pD0, off);
        pD1 += __shfl_xor(pD1, off);
      }
      if (c15 == 0 && gm < M) {
        as1[(size_t)gm * 8 + 2 * wn]     = pS0;
        as1[(size_t)gm * 8 + 2 * wn + 1] = pS1;
        ad1[(size_t)gm * 8 + 2 * wn]     = pD0;
        ad1[(size_t)gm * 8 + 2 * wn + 1] = pD1;
      }
    }
  }

  // ---- C store via per-wave LDS transpose: coalesced 16B stores ----
  // wave region 4KB: waves 0-3 in Ah, 4-7 in Al (both free after last barrier)
  unsigned short* cst = (w < 4) ? (Ah + w * 2048) : (Al + (w - 4) * 2048);
#pragma unroll
  for (int jh = 0; jh < 2; ++jh) {
#pragma unroll
    for (int i = 0; i < 4; ++i)
#pragma unroll
      for (int r = 0; r < 4; ++r) {
        int row = i * 16 + q * 4 + r;
        cst[row * 32 + c15]      = f2bf(acc[i][2 * jh][r]);
        cst[row * 32 + 16 + c15] = f2bf(acc[i][2 * jh + 1][r]);
      }
    // read back contiguous; lane covers 16B; full-line global writes
#pragma unroll
    for (int t2 = 0; t2 < 4; ++t2) {
      int idx = t2 * 64 + lane;
      int row = idx >> 2, chunk = lane & 3;
      u16x8 v = *(const u16x8*)&cst[idx * 8];
      int gm = brow + wm * 64 + row;
      if (gm < M)
        *(u16x8*)&h1b[(size_t)gm * 256 + wn * 64 + jh * 32 + chunk * 8] = v;
    }
  }
}

// ---------------- GEMM2: h2b = bf16( out1e @ W2 ), A bf16, W2 split (2-product) ----------------
__global__ __launch_bounds__(512, 4) void k_gemm2(
    const unsigned short* __restrict__ Ae,
    const unsigned short* __restrict__ Bth, const unsigned short* __restrict__ Btl,
    unsigned short* __restrict__ Cb, int M)
{
  __shared__ __align__(16) unsigned short As[256 * 64];
  const int t = threadIdx.x;
  const int lane = t & 63;
  const int w = t >> 6;
  const int lrow = lane & 15, lkb = lane >> 4;
  const int brow = blockIdx.x * 256;

  f32x4 acc[2][2];
#pragma unroll
  for (int i = 0; i < 2; ++i)
#pragma unroll
    for (int j = 0; j < 2; ++j) acc[i][j] = (f32x4){0.f, 0.f, 0.f, 0.f};

  for (int kt = 0; kt < 4; ++kt) {
    const int k0 = kt * 64;
#pragma unroll
    for (int r = 0; r < 4; ++r) {
      int id = r * 512 + t;
      int m = id >> 3, c = id & 7;
      size_t g = (size_t)(brow + m) * 256 + k0 + c * 8;
      *(u16x8*)&As[swz(m, c)] = *(const u16x8*)&Ae[g];
    }
    __syncthreads();
#pragma unroll
    for (int kk = 0; kk < 2; ++kk) {
      bf16x8 bh[2], bl[2];
#pragma unroll
      for (int j = 0; j < 2; ++j) {
        size_t g = (size_t)(j * 16 + lrow) * 256 + k0 + kk * 32 + lkb * 8;
        bh[j] = *(const bf16x8*)&Bth[g];
        bl[j] = *(const bf16x8*)&Btl[g];
      }
#pragma unroll
      for (int i = 0; i < 2; ++i) {
        int row = w * 32 + i * 16 + lrow;
        bf16x8 a = *(const bf16x8*)&As[swz(row, kk * 4 + lkb)];
#pragma unroll
        for (int j = 0; j < 2; ++j) {
          acc[i][j] = __builtin_amdgcn_mfma_f32_16x16x32_bf16(a, bh[j], acc[i][j], 0, 0, 0);
          acc[i][j] = __builtin_amdgcn_mfma_f32_16x16x32_bf16(a, bl[j], acc[i][j], 0, 0, 0);
        }
      }
    }
    __syncthreads();
  }

#pragma unroll
  for (int i = 0; i < 2; ++i) {
    int mbase = brow + w * 32 + i * 16 + (lane >> 4) * 4;
#pragma unroll
    for (int j = 0; j < 2; ++j) {
      int nc = j * 16 + (lane & 15);
#pragma unroll
      for (int r = 0; r < 4; ++r) {
        int gm = mbase + r;
        if (gm < M) Cb[(size_t)gm * 32 + nc] = f2bf(acc[i][j][r]);
      }
    }
  }
}

// ---------------- per-node attention-score precompute, layer 2 (bf16 h2) ----------------
__global__ __launch_bounds__(256) void k_srcdst2(const unsigned short* __restrict__ h2b,
    const float* __restrict__ a_src, const float* __restrict__ a_dst,
    float* __restrict__ as2, float* __restrict__ ad2, int n)
{
  int node = blockIdx.x * 4 + (threadIdx.x >> 6);
  if (node >= n) return;
  int lane = threadIdx.x & 63;
  if (lane < 32) {
    float hv = bf2f(h2b[(size_t)node * 32 + lane]);
    float ps = hv * a_src[lane];
    float pd = hv * a_dst[lane];
#pragma unroll
    for (int off = 1; off < 32; off <<= 1) {
      ps += __shfl_xor(ps, off);
      pd += __shfl_xor(pd, off);
    }
    if (lane == 0) { as2[node] = ps; ad2[node] = pd; }
  }
}

// ---------------- CSR build ----------------
__global__ void k_deg(const int* __restrict__ ei, int* __restrict__ deg, int E, int etot)
{
  int e = blockIdx.x * blockDim.x + threadIdx.x;
  if (e >= etot) return;
  int dst = (e < E) ? ei[E + e] : (e - E);
  atomicAdd(&deg[dst], 1);
}

__global__ void k_scan1(const int* __restrict__ deg, int* __restrict__ rowptr,
                        int* __restrict__ bsums, int n)
{
  __shared__ int sm[2][1024];
  int t = threadIdx.x, b = blockIdx.x;
  int i = b * 1024 + t;
  int v = (i < n) ? deg[i] : 0;
  sm[0][t] = v;
  __syncthreads();
  int pb = 0;
  for (int off = 1; off < 1024; off <<= 1) {
    int x = sm[pb][t];
    if (t >= off) x += sm[pb][t - off];
    sm[pb ^ 1][t] = x;
    pb ^= 1;
    __syncthreads();
  }
  if (i < n) rowptr[i] = sm[pb][t] - v;
  if (t == 1023) bsums[b] = sm[pb][1023];
}

__global__ void k_scan2(int* bsums, int nb)
{
  if (threadIdx.x == 0 && blockIdx.x == 0) {
    int run = 0;
    for (int b = 0; b < nb; ++b) { int t = bsums[b]; bsums[b] = run; run += t; }
  }
}

__global__ void k_scan3(int* __restrict__ rowptr, const int* __restrict__ bsums, int n, int etot)
{
  int i = blockIdx.x * blockDim.x + threadIdx.x;
  if (i < n) rowptr[i] += bsums[i >> 10];
  if (i == 0) rowptr[n] = etot;
}

__global__ void k_fill(const int* __restrict__ ei, const int* __restrict__ rowptr,
                       int* __restrict__ fillc, int* __restrict__ csrsrc, int E, int etot)
{
  int e = blockIdx.x * blockDim.x + threadIdx.x;
  if (e >= etot) return;
  int src, dst;
  if (e < E) { src = ei[e]; dst = ei[E + e]; }
  else { src = dst = e - E; }
  int pos = rowptr[dst] + atomicAdd(&fillc[dst], 1);
  csrsrc[pos] = src;
}

// ---------------- layer-1 aggregation: wave per node (all 8 heads), LDS alpha chunks ----------------
// (R4 structure, empirically ~76us) + fused ELU + bf16 out1e store.
__global__ __launch_bounds__(256) void k_agg1(const unsigned short* __restrict__ h1b,
    const float* __restrict__ as1, const float* __restrict__ ad1,
    const int* __restrict__ rowptr, const int* __restrict__ csrsrc,
    const float* __restrict__ b1, unsigned short* __restrict__ out1e, int n)
{
  __shared__ float alds[4][64][8];
  __shared__ int   slds[4][64];

  int ns = threadIdx.x >> 6;
  int node = blockIdx.x * 4 + ns;
  if (node >= n) return;
  int lane = threadIdx.x & 63;
  int r0 = rowptr[node];
  int deg = rowptr[node + 1] - r0;

  int h = lane & 7;
  int slot = lane >> 3;
  float adv = ad1[node * 8 + h];

  // pass A: s = sum exp(e)  (no-max softmax; |e| <~ 12, clamp guards)
  float s = 0.f;
  for (int k = slot; k < deg; k += 8) {
    int src = csrsrc[r0 + k];
    float e = fminf(lrelu(as1[src * 8 + h] + adv), 60.f);
    s += __expf(e);
  }
#pragma unroll
  for (int off = 8; off < 64; off <<= 1) s += __shfl_xor(s, off);
  float inv = 1.f / (s + 1e-16f);

  // pass B: chunked LDS alpha fill + coalesced ushort4 row gathers
  int hh = lane >> 3;
  float4 acc = make_float4(0.f, 0.f, 0.f, 0.f);

  for (int c0 = 0; c0 < deg; c0 += 64) {
#pragma unroll
    for (int r = 0; r < 8; ++r) {
      int kl = r * 8 + slot;
      int k = c0 + kl;
      if (k < deg) {
        int src = csrsrc[r0 + k];
        float e = fminf(lrelu(as1[src * 8 + h] + adv), 60.f);
        alds[ns][kl][h] = __expf(e) * inv;
        if (h == 0) slds[ns][kl] = src;
      }
    }
    int clen = (deg - c0 < 64) ? (deg - c0) : 64;
#pragma unroll 4
    for (int j = 0; j < clen; ++j) {
      float a = alds[ns][j][hh];
      int src = slds[ns][j];
      ushort4 hv = *(const ushort4*)&h1b[(size_t)src * 256 + lane * 4];
      acc.x = fmaf(a, bf2f(hv.x), acc.x);
      acc.y = fmaf(a, bf2f(hv.y), acc.y);
      acc.z = fmaf(a, bf2f(hv.z), acc.z);
      acc.w = fmaf(a, bf2f(hv.w), acc.w);
    }
  }
  float4 bv = *(const float4*)&b1[lane * 4];
  float ox = acc.x + bv.x, oy = acc.y + bv.y, oz = acc.z + bv.z, ow = acc.w + bv.w;
  ushort4 ob;
  ob.x = f2bf(ox > 0.f ? ox : expm1f(ox));
  ob.y = f2bf(oy > 0.f ? oy : expm1f(oy));
  ob.z = f2bf(oz > 0.f ? oz : expm1f(oz));
  ob.w = f2bf(ow > 0.f ? ow : expm1f(ow));
  *(ushort4*)&out1e[(size_t)node * 256 + lane * 4] = ob;
}

// ---------------- layer-2 aggregation: 8 lanes/edge, ushort4 gathers ----------------
__global__ __launch_bounds__(256) void k_agg2(const unsigned short* __restrict__ h2b,
    const float* __restrict__ as2, const float* __restrict__ ad2,
    const int* __restrict__ rowptr, const int* __restrict__ csrsrc,
    const float* __restrict__ b2, float* __restrict__ out, int n)
{
  const int wid = threadIdx.x >> 6;
  const int lane = threadIdx.x & 63;
  const int node = blockIdx.x * 4 + wid;
  if (node >= n) return;

  const int r0 = rowptr[node];
  const int deg = rowptr[node + 1] - r0;
  const float adv = ad2[node];

  const int c4 = lane & 7;
  const int es = lane >> 3;
  float s = 0.f;
  float ax = 0.f, ay = 0.f, az = 0.f, aw = 0.f;

  const int dfull = deg & ~7;
#pragma unroll 2
  for (int c0 = 0; c0 < dfull; c0 += 8) {
    int src = csrsrc[r0 + c0 + es];
    float e = fminf(lrelu(as2[src] + adv), 60.f);
    float ex = __expf(e);
    s += ex;
    ushort4 hv = *(const ushort4*)&h2b[(size_t)src * 32 + c4 * 4];
    ax = fmaf(ex, bf2f(hv.x), ax);
    ay = fmaf(ex, bf2f(hv.y), ay);
    az = fmaf(ex, bf2f(hv.z), az);
    aw = fmaf(ex, bf2f(hv.w), aw);
  }
  if (dfull + es < deg) {
    int src = csrsrc[r0 + dfull + es];
    float e = fminf(lrelu(as2[src] + adv), 60.f);
    float ex = __expf(e);
    s += ex;
    ushort4 hv = *(const ushort4*)&h2b[(size_t)src * 32 + c4 * 4];
    ax = fmaf(ex, bf2f(hv.x), ax);
    ay = fmaf(ex, bf2f(hv.y), ay);
    az = fmaf(ex, bf2f(hv.z), az);
    aw = fmaf(ex, bf2f(hv.w), aw);
  }
#pragma unroll
  for (int off = 8; off < 64; off <<= 1) {
    s  += __shfl_xor(s, off);
    ax += __shfl_xor(ax, off);
    ay += __shfl_xor(ay, off);
    az += __shfl_xor(az, off);
    aw += __shfl_xor(aw, off);
  }
  if (es == 0) {
    float inv = 1.f / (s + 1e-16f);
    float4 o;
    o.x = ax * inv + b2[c4 * 4 + 0];
    o.y = ay * inv + b2[c4 * 4 + 1];
    o.z = az * inv + b2[c4 * 4 + 2];
    o.w = aw * inv + b2[c4 * 4 + 3];
    *(float4*)&out[(size_t)node * 32 + c4 * 4] = o;
  }
}

// ---------------- host launch ----------------
extern "C" void kernel_launch(void* const* d_in, const int* in_sizes, int n_in,
                              void* d_out, int out_size, void* d_ws, size_t ws_size,
                              hipStream_t stream)
{
  const float* x      = (const float*)d_in[0];
  const int*   ei     = (const int*)d_in[1];
  const float* W1     = (const float*)d_in[3];
  const float* a_src1 = (const float*)d_in[4];
  const float* a_dst1 = (const float*)d_in[5];
  const float* b1     = (const float*)d_in[6];
  const float* W2     = (const float*)d_in[7];
  const float* a_src2 = (const float*)d_in[8];
  const float* a_dst2 = (const float*)d_in[9];
  const float* b2     = (const float*)d_in[10];
  float* out = (float*)d_out;

  const int n = in_sizes[0] / 256;            // 50000
  const int E = in_sizes[2];                  // 800000
  const int etot = E + n;
  const int Mpad = ((n + 255) / 256) * 256;   // 50176

  // workspace carve
  unsigned short* h1b   = (unsigned short*)d_ws;           // [n][256] bf16 node-major
  unsigned short* out1e = h1b + (size_t)n * 256;           // [Mpad][256] bf16
  unsigned short* h2b   = out1e + (size_t)Mpad * 256;      // n*32 bf16
  float* as1v = (float*)(h2b + (size_t)n * 32);            // [n][8]
  float* ad1v = as1v + (size_t)n * 8;                      // [n][8]
  float* as2v = ad1v + (size_t)n * 8;                      // n
  float* ad2v = as2v + n;                                  // n
  int* rowptr = (int*)(ad2v + n);                          // n+1
  int* degc   = rowptr + (n + 1);                          // n
  int* fillc  = degc + n;                                  // n
  int* csrsrc = fillc + n;                                 // etot
  int* bsums  = csrsrc + etot;                             // <=64
  unsigned short* wth  = (unsigned short*)(bsums + 64);    // 65536
  unsigned short* wtl  = wth + 65536;                      // 65536
  unsigned short* w2th = wtl + 65536;                      // 8192
  unsigned short* w2tl = w2th + 8192;                      // 8192

  hipMemsetAsync(degc, 0, (size_t)2 * n * sizeof(int), stream);

  // weight splits
  k_splitW<<<256, 256, 0, stream>>>(W1, wth, wtl);
  k_splitW2<<<32, 256, 0, stream>>>(W2, w2th, w2tl);

  // h1b/as1/ad1 = gemm1(x, W1) fused
  k_gemm1<<<Mpad / 128, 512, 0, stream>>>(x, wth, wtl, a_src1, a_dst1,
                                          h1b, as1v, ad1v, n);

  // CSR build
  int eb = (etot + 255) / 256;
  k_deg<<<eb, 256, 0, stream>>>(ei, degc, E, etot);
  int nblk = (n + 1023) / 1024;
  k_scan1<<<nblk, 1024, 0, stream>>>(degc, rowptr, bsums, n);
  k_scan2<<<1, 64, 0, stream>>>(bsums, nblk);
  k_scan3<<<(n + 255) / 256, 256, 0, stream>>>(rowptr, bsums, n, etot);
  k_fill<<<eb, 256, 0, stream>>>(ei, rowptr, fillc, csrsrc, E, etot);

  // layer-1 attention (wave per node, all heads)
  int nb4 = (n + 3) / 4;
  k_agg1<<<nb4, 256, 0, stream>>>(h1b, as1v, ad1v, rowptr, csrsrc, b1, out1e, n);

  // h2b = bf16(out1e @ W2)
  k_gemm2<<<Mpad / 256, 512, 0, stream>>>(out1e, w2th, w2tl, h2b, n);

  // layer-2 attention -> output
  k_srcdst2<<<nb4, 256, 0, stream>>>(h2b, a_src2, a_dst2, as2v, ad2v, n);
  k_agg2<<<nb4, 256, 0, stream>>>(h2b, as2v, ad2v, rowptr, csrsrc, b2, out, n);
}

// Round 9
// 275.502 us; speedup vs baseline: 1.4835x; 1.0907x over previous
//
#include <hip/hip_runtime.h>
#include <math.h>

typedef __attribute__((ext_vector_type(8))) short bf16x8;
typedef __attribute__((ext_vector_type(8))) unsigned short u16x8;
typedef __attribute__((ext_vector_type(4))) float f32x4;

__device__ __forceinline__ float lrelu(float x) { return x > 0.f ? x : 0.2f * x; }

__device__ __forceinline__ unsigned short f2bf(float f) {
  unsigned int u = __float_as_uint(f);
  unsigned int r = (u + 0x7FFFu + ((u >> 16) & 1u)) >> 16;   // RNE
  return (unsigned short)r;
}
__device__ __forceinline__ float bf2f(unsigned short h) {
  return __uint_as_float(((unsigned int)h) << 16);
}

// swizzled LDS offset (in shorts) for [rows][64]bf16 tile: 16B chunk c16 of row
__device__ __forceinline__ int swz(int row, int c16) {
  return (row * 8 + (c16 ^ (row & 7))) * 8;
}

// ---------------- W1 split+transpose: [256][256] -> hi/lo [n][k] ----------------
__global__ __launch_bounds__(256) void k_splitW(const float* __restrict__ W,
    unsigned short* __restrict__ Wth, unsigned short* __restrict__ Wtl)
{
  int nn = blockIdx.x;      // 256
  int k = threadIdx.x;      // 256
  float v = W[k * 256 + nn];
  unsigned short h = f2bf(v);
  unsigned short l = f2bf(v - bf2f(h));
  Wth[nn * 256 + k] = h;
  Wtl[nn * 256 + k] = l;
}

// ---------------- W2 split+transpose: [256][32] -> hi/lo [32][256] ----------------
__global__ __launch_bounds__(256) void k_splitW2(const float* __restrict__ W,
    unsigned short* __restrict__ Wth, unsigned short* __restrict__ Wtl)
{
  int nn = blockIdx.x;      // 32
  int k = threadIdx.x;      // 256
  float v = W[k * 32 + nn];
  unsigned short h = f2bf(v);
  unsigned short l = f2bf(v - bf2f(h));
  Wth[nn * 256 + k] = h;
  Wtl[nn * 256 + k] = l;
}

// ---------------- GEMM1: BM=64, wave-per-head, register prefetch ----------------
// grid = Mpad/64 (784): ~3 blocks/CU. Epilogue: fused as1/ad1 + LDS-transposed C store.
__global__ __launch_bounds__(512, 4) void k_gemm1(
    const float* __restrict__ X,
    const unsigned short* __restrict__ Bth, const unsigned short* __restrict__ Btl,
    const float* __restrict__ a_src, const float* __restrict__ a_dst,
    unsigned short* __restrict__ h1b, float* __restrict__ as1, float* __restrict__ ad1,
    int M)
{
  __shared__ __align__(16) unsigned short Ah[64 * 64];     // 8KB
  __shared__ __align__(16) unsigned short Al[64 * 64];     // 8KB
  __shared__ __align__(16) unsigned short Cst[8 * 64 * 32]; // 32KB
  const int t = threadIdx.x;
  const int lane = t & 63;
  const int w = t >> 6;               // wave = head, owns cols w*32..w*32+31
  const int lrow = lane & 15, lkb = lane >> 4;
  const int brow = blockIdx.x * 64;

  f32x4 acc[4][2];
#pragma unroll
  for (int i = 0; i < 4; ++i)
#pragma unroll
    for (int j = 0; j < 2; ++j) acc[i][j] = (f32x4){0.f, 0.f, 0.f, 0.f};

  // prefetch k-tile 0
  float4 pref[2];
#pragma unroll
  for (int r = 0; r < 2; ++r) {
    int id = r * 512 + t, m = id >> 4, cq = id & 15, gm = brow + m;
    pref[r] = (gm < M) ? *(const float4*)&X[(size_t)gm * 256 + cq * 4]
                       : make_float4(0.f, 0.f, 0.f, 0.f);
  }

  for (int kt = 0; kt < 4; ++kt) {
    const int k0 = kt * 64;
    // consume prefetch: split fp32 -> bf16 hi/lo into swizzled LDS
#pragma unroll
    for (int r = 0; r < 2; ++r) {
      int id = r * 512 + t, m = id >> 4, cq = id & 15;
      float4 v = pref[r];
      unsigned short h0 = f2bf(v.x), h1 = f2bf(v.y), h2 = f2bf(v.z), h3 = f2bf(v.w);
      unsigned short l0 = f2bf(v.x - bf2f(h0)), l1 = f2bf(v.y - bf2f(h1));
      unsigned short l2 = f2bf(v.z - bf2f(h2)), l3 = f2bf(v.w - bf2f(h3));
      int off = swz(m, cq >> 1) + (cq & 1) * 4;
      *(uint2*)&Ah[off] = make_uint2((unsigned)h0 | ((unsigned)h1 << 16),
                                     (unsigned)h2 | ((unsigned)h3 << 16));
      *(uint2*)&Al[off] = make_uint2((unsigned)l0 | ((unsigned)l1 << 16),
                                     (unsigned)l2 | ((unsigned)l3 << 16));
    }
    // issue next k-tile loads before the barrier (latency overlaps MFMA phase)
    if (kt < 3) {
#pragma unroll
      for (int r = 0; r < 2; ++r) {
        int id = r * 512 + t, m = id >> 4, cq = id & 15, gm = brow + m;
        pref[r] = (gm < M) ? *(const float4*)&X[(size_t)gm * 256 + k0 + 64 + cq * 4]
                           : make_float4(0.f, 0.f, 0.f, 0.f);
      }
    }
    __syncthreads();
#pragma unroll
    for (int kk = 0; kk < 2; ++kk) {
      bf16x8 bh[2], bl[2];
#pragma unroll
      for (int j = 0; j < 2; ++j) {
        size_t g = (size_t)(w * 32 + j * 16 + lrow) * 256 + k0 + kk * 32 + lkb * 8;
        bh[j] = *(const bf16x8*)&Bth[g];
        bl[j] = *(const bf16x8*)&Btl[g];
      }
#pragma unroll
      for (int i = 0; i < 4; ++i) {
        int row = i * 16 + lrow;
        int lo = swz(row, kk * 4 + lkb);
        bf16x8 ah = *(const bf16x8*)&Ah[lo];
        bf16x8 al = *(const bf16x8*)&Al[lo];
#pragma unroll
        for (int j = 0; j < 2; ++j) {
          acc[i][j] = __builtin_amdgcn_mfma_f32_16x16x32_bf16(ah, bh[j], acc[i][j], 0, 0, 0);
          acc[i][j] = __builtin_amdgcn_mfma_f32_16x16x32_bf16(ah, bl[j], acc[i][j], 0, 0, 0);
          acc[i][j] = __builtin_amdgcn_mfma_f32_16x16x32_bf16(al, bh[j], acc[i][j], 0, 0, 0);
        }
      }
    }
    __syncthreads();
  }

  const int c15 = lane & 15, q = lane >> 4;

  // fused as1/ad1 for head w, interleaved [n][8]
  float asv[2], adv[2];
#pragma unroll
  for (int j = 0; j < 2; ++j) {
    int idx = w * 32 + j * 16 + c15;
    asv[j] = a_src[idx];
    adv[j] = a_dst[idx];
  }
#pragma unroll
  for (int i = 0; i < 4; ++i) {
#pragma unroll
    for (int r = 0; r < 4; ++r) {
      int gm = brow + i * 16 + q * 4 + r;
      float pS = acc[i][0][r] * asv[0] + acc[i][1][r] * asv[1];
      float pD = acc[i][0][r] * adv[0] + acc[i][1][r] * adv[1];
#pragma unroll
      for (int off = 1; off < 16; off <<= 1) {
        pS += __shfl_xor(pS, off);
        pD += __shfl_xor(pD, off);
      }
      if (c15 == 0 && gm < M) {
        as1[(size_t)gm * 8 + w] = pS;
        ad1[(size_t)gm * 8 + w] = pD;
      }
    }
  }

  // C store via per-wave LDS transpose -> coalesced 16B stores (node-major h1b)
  unsigned short* cst = Cst + w * 2048;
#pragma unroll
  for (int i = 0; i < 4; ++i)
#pragma unroll
    for (int j = 0; j < 2; ++j)
#pragma unroll
      for (int r = 0; r < 4; ++r) {
        int row = i * 16 + q * 4 + r;
        cst[row * 32 + j * 16 + c15] = f2bf(acc[i][j][r]);
      }
  // same-wave write->read: compiler orders LDS deps
#pragma unroll
  for (int t2 = 0; t2 < 4; ++t2) {
    int idx = t2 * 64 + lane;
    int row = idx >> 2, ch = idx & 3;
    u16x8 v = *(const u16x8*)&cst[row * 32 + ch * 8];
    int gm = brow + row;
    if (gm < M)
      *(u16x8*)&h1b[(size_t)gm * 256 + w * 32 + ch * 8] = v;
  }
}

// ---------------- GEMM2 fused: h2b = bf16(out1e @ W2) + as2/ad2 epilogue ----------------
// No LDS, no barriers: A rows are wave-private bf16 in MFMA-ready layout (L2 gather),
// B (W2T hi/lo, 32KB) L2-resident.
__global__ __launch_bounds__(512) void k_gemm2(
    const unsigned short* __restrict__ Ae,
    const unsigned short* __restrict__ Bth, const unsigned short* __restrict__ Btl,
    const float* __restrict__ a_src, const float* __restrict__ a_dst,
    unsigned short* __restrict__ h2b, float* __restrict__ as2, float* __restrict__ ad2,
    int M)
{
  const int t = threadIdx.x, lane = t & 63, w = t >> 6;
  const int lrow = lane & 15, lkb = lane >> 4;
  const int grow = blockIdx.x * 128 + w * 16;   // wave's 16 rows

  f32x4 acc[2];
  acc[0] = (f32x4){0.f, 0.f, 0.f, 0.f};
  acc[1] = (f32x4){0.f, 0.f, 0.f, 0.f};

#pragma unroll
  for (int kt = 0; kt < 4; ++kt) {
    const int k0 = kt * 64;
#pragma unroll
    for (int kk = 0; kk < 2; ++kk) {
      bf16x8 a = *(const bf16x8*)&Ae[(size_t)(grow + lrow) * 256 + k0 + kk * 32 + lkb * 8];
#pragma unroll
      for (int j = 0; j < 2; ++j) {
        size_t g = (size_t)(j * 16 + lrow) * 256 + k0 + kk * 32 + lkb * 8;
        bf16x8 bh = *(const bf16x8*)&Bth[g];
        bf16x8 bl = *(const bf16x8*)&Btl[g];
        acc[j] = __builtin_amdgcn_mfma_f32_16x16x32_bf16(a, bh, acc[j], 0, 0, 0);
        acc[j] = __builtin_amdgcn_mfma_f32_16x16x32_bf16(a, bl, acc[j], 0, 0, 0);
      }
    }
  }

  const int c15 = lane & 15, q = lane >> 4;
  float asv[2] = { a_src[c15], a_src[16 + c15] };
  float adv[2] = { a_dst[c15], a_dst[16 + c15] };
#pragma unroll
  for (int r = 0; r < 4; ++r) {
    int gm = grow + q * 4 + r;
    float pS = acc[0][r] * asv[0] + acc[1][r] * asv[1];
    float pD = acc[0][r] * adv[0] + acc[1][r] * adv[1];
#pragma unroll
    for (int off = 1; off < 16; off <<= 1) {
      pS += __shfl_xor(pS, off);
      pD += __shfl_xor(pD, off);
    }
    if (c15 == 0 && gm < M) { as2[gm] = pS; ad2[gm] = pD; }
    if (gm < M) {
      h2b[(size_t)gm * 32 + c15]      = f2bf(acc[0][r]);
      h2b[(size_t)gm * 32 + 16 + c15] = f2bf(acc[1][r]);
    }
  }
}

// ---------------- CSR build ----------------
__global__ void k_deg(const int* __restrict__ ei, int* __restrict__ deg, int E, int etot)
{
  int e = blockIdx.x * blockDim.x + threadIdx.x;
  if (e >= etot) return;
  int dst = (e < E) ? ei[E + e] : (e - E);
  atomicAdd(&deg[dst], 1);
}

__global__ void k_scan1(const int* __restrict__ deg, int* __restrict__ rowptr,
                        int* __restrict__ bsums, int n)
{
  __shared__ int sm[2][1024];
  int t = threadIdx.x, b = blockIdx.x;
  int i = b * 1024 + t;
  int v = (i < n) ? deg[i] : 0;
  sm[0][t] = v;
  __syncthreads();
  int pb = 0;
  for (int off = 1; off < 1024; off <<= 1) {
    int x = sm[pb][t];
    if (t >= off) x += sm[pb][t - off];
    sm[pb ^ 1][t] = x;
    pb ^= 1;
    __syncthreads();
  }
  if (i < n) rowptr[i] = sm[pb][t] - v;
  if (t == 1023) bsums[b] = sm[pb][1023];
}

__global__ void k_scan2(int* bsums, int nb)
{
  if (threadIdx.x == 0 && blockIdx.x == 0) {
    int run = 0;
    for (int b = 0; b < nb; ++b) { int t = bsums[b]; bsums[b] = run; run += t; }
  }
}

__global__ void k_scan3(int* __restrict__ rowptr, const int* __restrict__ bsums, int n, int etot)
{
  int i = blockIdx.x * blockDim.x + threadIdx.x;
  if (i < n) rowptr[i] += bsums[i >> 10];
  if (i == 0) rowptr[n] = etot;
}

__global__ void k_fill(const int* __restrict__ ei, const int* __restrict__ rowptr,
                       int* __restrict__ fillc, int* __restrict__ csrsrc, int E, int etot)
{
  int e = blockIdx.x * blockDim.x + threadIdx.x;
  if (e >= etot) return;
  int src, dst;
  if (e < E) { src = ei[e]; dst = ei[E + e]; }
  else { src = dst = e - E; }
  int pos = rowptr[dst] + atomicAdd(&fillc[dst], 1);
  csrsrc[pos] = src;
}

// ---------------- layer-1 aggregation: wave per node (all 8 heads), LDS alpha chunks ----------------
__global__ __launch_bounds__(256) void k_agg1(const unsigned short* __restrict__ h1b,
    const float* __restrict__ as1, const float* __restrict__ ad1,
    const int* __restrict__ rowptr, const int* __restrict__ csrsrc,
    const float* __restrict__ b1, unsigned short* __restrict__ out1e, int n)
{
  __shared__ float alds[4][64][8];
  __shared__ int   slds[4][64];

  int ns = threadIdx.x >> 6;
  int node = blockIdx.x * 4 + ns;
  if (node >= n) return;
  int lane = threadIdx.x & 63;
  int r0 = rowptr[node];
  int deg = rowptr[node + 1] - r0;

  int h = lane & 7;
  int slot = lane >> 3;
  float adv = ad1[node * 8 + h];

  float s = 0.f;
  for (int k = slot; k < deg; k += 8) {
    int src = csrsrc[r0 + k];
    float e = fminf(lrelu(as1[src * 8 + h] + adv), 60.f);
    s += __expf(e);
  }
#pragma unroll
  for (int off = 8; off < 64; off <<= 1) s += __shfl_xor(s, off);
  float inv = 1.f / (s + 1e-16f);

  int hh = lane >> 3;
  float4 acc = make_float4(0.f, 0.f, 0.f, 0.f);

  for (int c0 = 0; c0 < deg; c0 += 64) {
#pragma unroll
    for (int r = 0; r < 8; ++r) {
      int kl = r * 8 + slot;
      int k = c0 + kl;
      if (k < deg) {
        int src = csrsrc[r0 + k];
        float e = fminf(lrelu(as1[src * 8 + h] + adv), 60.f);
        alds[ns][kl][h] = __expf(e) * inv;
        if (h == 0) slds[ns][kl] = src;
      }
    }
    int clen = (deg - c0 < 64) ? (deg - c0) : 64;
#pragma unroll 4
    for (int j = 0; j < clen; ++j) {
      float a = alds[ns][j][hh];
      int src = slds[ns][j];
      ushort4 hv = *(const ushort4*)&h1b[(size_t)src * 256 + lane * 4];
      acc.x = fmaf(a, bf2f(hv.x), acc.x);
      acc.y = fmaf(a, bf2f(hv.y), acc.y);
      acc.z = fmaf(a, bf2f(hv.z), acc.z);
      acc.w = fmaf(a, bf2f(hv.w), acc.w);
    }
  }
  float4 bv = *(const float4*)&b1[lane * 4];
  float ox = acc.x + bv.x, oy = acc.y + bv.y, oz = acc.z + bv.z, ow = acc.w + bv.w;
  ushort4 ob;
  ob.x = f2bf(ox > 0.f ? ox : expm1f(ox));
  ob.y = f2bf(oy > 0.f ? oy : expm1f(oy));
  ob.z = f2bf(oz > 0.f ? oz : expm1f(oz));
  ob.w = f2bf(ow > 0.f ? ow : expm1f(ow));
  *(ushort4*)&out1e[(size_t)node * 256 + lane * 4] = ob;
}

// ---------------- layer-2 aggregation: 8 lanes/edge, ushort4 gathers ----------------
__global__ __launch_bounds__(256) void k_agg2(const unsigned short* __restrict__ h2b,
    const float* __restrict__ as2, const float* __restrict__ ad2,
    const int* __restrict__ rowptr, const int* __restrict__ csrsrc,
    const float* __restrict__ b2, float* __restrict__ out, int n)
{
  const int wid = threadIdx.x >> 6;
  const int lane = threadIdx.x & 63;
  const int node = blockIdx.x * 4 + wid;
  if (node >= n) return;

  const int r0 = rowptr[node];
  const int deg = rowptr[node + 1] - r0;
  const float adv = ad2[node];

  const int c4 = lane & 7;
  const int es = lane >> 3;
  float s = 0.f;
  float ax = 0.f, ay = 0.f, az = 0.f, aw = 0.f;

  const int dfull = deg & ~7;
#pragma unroll 2
  for (int c0 = 0; c0 < dfull; c0 += 8) {
    int src = csrsrc[r0 + c0 + es];
    float e = fminf(lrelu(as2[src] + adv), 60.f);
    float ex = __expf(e);
    s += ex;
    ushort4 hv = *(const ushort4*)&h2b[(size_t)src * 32 + c4 * 4];
    ax = fmaf(ex, bf2f(hv.x), ax);
    ay = fmaf(ex, bf2f(hv.y), ay);
    az = fmaf(ex, bf2f(hv.z), az);
    aw = fmaf(ex, bf2f(hv.w), aw);
  }
  if (dfull + es < deg) {
    int src = csrsrc[r0 + dfull + es];
    float e = fminf(lrelu(as2[src] + adv), 60.f);
    float ex = __expf(e);
    s += ex;
    ushort4 hv = *(const ushort4*)&h2b[(size_t)src * 32 + c4 * 4];
    ax = fmaf(ex, bf2f(hv.x), ax);
    ay = fmaf(ex, bf2f(hv.y), ay);
    az = fmaf(ex, bf2f(hv.z), az);
    aw = fmaf(ex, bf2f(hv.w), aw);
  }
#pragma unroll
  for (int off = 8; off < 64; off <<= 1) {
    s  += __shfl_xor(s, off);
    ax += __shfl_xor(ax, off);
    ay += __shfl_xor(ay, off);
    az += __shfl_xor(az, off);
    aw += __shfl_xor(aw, off);
  }
  if (es == 0) {
    float inv = 1.f / (s + 1e-16f);
    float4 o;
    o.x = ax * inv + b2[c4 * 4 + 0];
    o.y = ay * inv + b2[c4 * 4 + 1];
    o.z = az * inv + b2[c4 * 4 + 2];
    o.w = aw * inv + b2[c4 * 4 + 3];
    *(float4*)&out[(size_t)node * 32 + c4 * 4] = o;
  }
}

// ---------------- host launch ----------------
extern "C" void kernel_launch(void* const* d_in, const int* in_sizes, int n_in,
                              void* d_out, int out_size, void* d_ws, size_t ws_size,
                              hipStream_t stream)
{
  const float* x      = (const float*)d_in[0];
  const int*   ei     = (const int*)d_in[1];
  const float* W1     = (const float*)d_in[3];
  const float* a_src1 = (const float*)d_in[4];
  const float* a_dst1 = (const float*)d_in[5];
  const float* b1     = (const float*)d_in[6];
  const float* W2     = (const float*)d_in[7];
  const float* a_src2 = (const float*)d_in[8];
  const float* a_dst2 = (const float*)d_in[9];
  const float* b2     = (const float*)d_in[10];
  float* out = (float*)d_out;

  const int n = in_sizes[0] / 256;            // 50000
  const int E = in_sizes[2];                  // 800000
  const int etot = E + n;
  const int Mpad = ((n + 255) / 256) * 256;   // 50176

  // workspace carve
  unsigned short* h1b   = (unsigned short*)d_ws;           // [n][256] bf16 node-major
  unsigned short* out1e = h1b + (size_t)n * 256;           // [Mpad][256] bf16
  unsigned short* h2b   = out1e + (size_t)Mpad * 256;      // n*32 bf16
  float* as1v = (float*)(h2b + (size_t)n * 32);            // [n][8]
  float* ad1v = as1v + (size_t)n * 8;                      // [n][8]
  float* as2v = ad1v + (size_t)n * 8;                      // n
  float* ad2v = as2v + n;                                  // n
  int* rowptr = (int*)(ad2v + n);                          // n+1
  int* degc   = rowptr + (n + 1);                          // n
  int* fillc  = degc + n;                                  // n
  int* csrsrc = fillc + n;                                 // etot
  int* bsums  = csrsrc + etot;                             // <=64
  unsigned short* wth  = (unsigned short*)(bsums + 64);    // 65536
  unsigned short* wtl  = wth + 65536;                      // 65536
  unsigned short* w2th = wtl + 65536;                      // 8192
  unsigned short* w2tl = w2th + 8192;                      // 8192

  hipMemsetAsync(degc, 0, (size_t)2 * n * sizeof(int), stream);

  // weight splits
  k_splitW<<<256, 256, 0, stream>>>(W1, wth, wtl);
  k_splitW2<<<32, 256, 0, stream>>>(W2, w2th, w2tl);

  // h1b/as1/ad1 = gemm1(x, W1) fused
  k_gemm1<<<Mpad / 64, 512, 0, stream>>>(x, wth, wtl, a_src1, a_dst1,
                                         h1b, as1v, ad1v, n);

  // CSR build
  int eb = (etot + 255) / 256;
  k_deg<<<eb, 256, 0, stream>>>(ei, degc, E, etot);
  int nblk = (n + 1023) / 1024;
  k_scan1<<<nblk, 1024, 0, stream>>>(degc, rowptr, bsums, n);
  k_scan2<<<1, 64, 0, stream>>>(bsums, nblk);
  k_scan3<<<(n + 255) / 256, 256, 0, stream>>>(rowptr, bsums, n, etot);
  k_fill<<<eb, 256, 0, stream>>>(ei, rowptr, fillc, csrsrc, E, etot);

  // layer-1 attention (wave per node, all heads)
  int nb4 = (n + 3) / 4;
  k_agg1<<<nb4, 256, 0, stream>>>(h1b, as1v, ad1v, rowptr, csrsrc, b1, out1e, n);

  // h2b/as2/ad2 = gemm2(out1e, W2) fused
  k_gemm2<<<Mpad / 128, 512, 0, stream>>>(out1e, w2th, w2tl, a_src2, a_dst2,
                                          h2b, as2v, ad2v, n);

  // layer-2 attention -> output
  k_agg2<<<nb4, 256, 0, stream>>>(h2b, as2v, ad2v, rowptr, csrsrc, b2, out, n);
}

// Round 10
// 259.491 us; speedup vs baseline: 1.5751x; 1.0617x over previous
//
#include <hip/hip_runtime.h>
#include <math.h>

typedef __attribute__((ext_vector_type(8))) short bf16x8;
typedef __attribute__((ext_vector_type(8))) unsigned short u16x8;
typedef __attribute__((ext_vector_type(4))) float f32x4;

__device__ __forceinline__ float lrelu(float x) { return x > 0.f ? x : 0.2f * x; }

__device__ __forceinline__ unsigned short f2bf(float f) {
  unsigned int u = __float_as_uint(f);
  unsigned int r = (u + 0x7FFFu + ((u >> 16) & 1u)) >> 16;   // RNE
  return (unsigned short)r;
}
__device__ __forceinline__ float bf2f(unsigned short h) {
  return __uint_as_float(((unsigned int)h) << 16);
}

// swizzled LDS offset (in shorts) for [rows][64]bf16 tile: 16B chunk c16 of row
__device__ __forceinline__ int swz(int row, int c16) {
  return (row * 8 + (c16 ^ (row & 7))) * 8;
}

// ---------------- prep: W1/W2 split+transpose + zero degree/fill counters ----------------
// blocks 0-255: W1 column nn; blocks 256-287: W2 column nn-256. All blocks help zero.
__global__ __launch_bounds__(256) void k_prep(const float* __restrict__ W1,
    const float* __restrict__ W2,
    unsigned short* __restrict__ Wth, unsigned short* __restrict__ Wtl,
    unsigned short* __restrict__ W2th, unsigned short* __restrict__ W2tl,
    int* __restrict__ zeros, int nz)
{
  int bid = blockIdx.x, t = threadIdx.x;
  if (bid < 256) {
    float v = W1[t * 256 + bid];
    unsigned short h = f2bf(v);
    Wth[bid * 256 + t] = h;
    Wtl[bid * 256 + t] = f2bf(v - bf2f(h));
  } else {
    int nn = bid - 256;
    float v = W2[t * 32 + nn];
    unsigned short h = f2bf(v);
    W2th[nn * 256 + t] = h;
    W2tl[nn * 256 + t] = f2bf(v - bf2f(h));
  }
  for (int i = bid * 256 + t; i < nz; i += gridDim.x * 256) zeros[i] = 0;
}

// ---------------- GEMM1: BM=64, wave-per-head, register prefetch ----------------
__global__ __launch_bounds__(512, 4) void k_gemm1(
    const float* __restrict__ X,
    const unsigned short* __restrict__ Bth, const unsigned short* __restrict__ Btl,
    const float* __restrict__ a_src, const float* __restrict__ a_dst,
    unsigned short* __restrict__ h1b, float* __restrict__ as1, float* __restrict__ ad1,
    int M)
{
  __shared__ __align__(16) unsigned short Ah[64 * 64];
  __shared__ __align__(16) unsigned short Al[64 * 64];
  __shared__ __align__(16) unsigned short Cst[8 * 64 * 32];
  const int t = threadIdx.x;
  const int lane = t & 63;
  const int w = t >> 6;               // wave = head
  const int lrow = lane & 15, lkb = lane >> 4;
  const int brow = blockIdx.x * 64;

  f32x4 acc[4][2];
#pragma unroll
  for (int i = 0; i < 4; ++i)
#pragma unroll
    for (int j = 0; j < 2; ++j) acc[i][j] = (f32x4){0.f, 0.f, 0.f, 0.f};

  float4 pref[2];
#pragma unroll
  for (int r = 0; r < 2; ++r) {
    int id = r * 512 + t, m = id >> 4, cq = id & 15, gm = brow + m;
    pref[r] = (gm < M) ? *(const float4*)&X[(size_t)gm * 256 + cq * 4]
                       : make_float4(0.f, 0.f, 0.f, 0.f);
  }

  for (int kt = 0; kt < 4; ++kt) {
    const int k0 = kt * 64;
#pragma unroll
    for (int r = 0; r < 2; ++r) {
      int id = r * 512 + t, m = id >> 4, cq = id & 15;
      float4 v = pref[r];
      unsigned short h0 = f2bf(v.x), h1 = f2bf(v.y), h2 = f2bf(v.z), h3 = f2bf(v.w);
      unsigned short l0 = f2bf(v.x - bf2f(h0)), l1 = f2bf(v.y - bf2f(h1));
      unsigned short l2 = f2bf(v.z - bf2f(h2)), l3 = f2bf(v.w - bf2f(h3));
      int off = swz(m, cq >> 1) + (cq & 1) * 4;
      *(uint2*)&Ah[off] = make_uint2((unsigned)h0 | ((unsigned)h1 << 16),
                                     (unsigned)h2 | ((unsigned)h3 << 16));
      *(uint2*)&Al[off] = make_uint2((unsigned)l0 | ((unsigned)l1 << 16),
                                     (unsigned)l2 | ((unsigned)l3 << 16));
    }
    if (kt < 3) {
#pragma unroll
      for (int r = 0; r < 2; ++r) {
        int id = r * 512 + t, m = id >> 4, cq = id & 15, gm = brow + m;
        pref[r] = (gm < M) ? *(const float4*)&X[(size_t)gm * 256 + k0 + 64 + cq * 4]
                           : make_float4(0.f, 0.f, 0.f, 0.f);
      }
    }
    __syncthreads();
#pragma unroll
    for (int kk = 0; kk < 2; ++kk) {
      bf16x8 bh[2], bl[2];
#pragma unroll
      for (int j = 0; j < 2; ++j) {
        size_t g = (size_t)(w * 32 + j * 16 + lrow) * 256 + k0 + kk * 32 + lkb * 8;
        bh[j] = *(const bf16x8*)&Bth[g];
        bl[j] = *(const bf16x8*)&Btl[g];
      }
#pragma unroll
      for (int i = 0; i < 4; ++i) {
        int row = i * 16 + lrow;
        int lo = swz(row, kk * 4 + lkb);
        bf16x8 ah = *(const bf16x8*)&Ah[lo];
        bf16x8 al = *(const bf16x8*)&Al[lo];
#pragma unroll
        for (int j = 0; j < 2; ++j) {
          acc[i][j] = __builtin_amdgcn_mfma_f32_16x16x32_bf16(ah, bh[j], acc[i][j], 0, 0, 0);
          acc[i][j] = __builtin_amdgcn_mfma_f32_16x16x32_bf16(ah, bl[j], acc[i][j], 0, 0, 0);
          acc[i][j] = __builtin_amdgcn_mfma_f32_16x16x32_bf16(al, bh[j], acc[i][j], 0, 0, 0);
        }
      }
    }
    __syncthreads();
  }

  const int c15 = lane & 15, q = lane >> 4;

  float asv[2], adv[2];
#pragma unroll
  for (int j = 0; j < 2; ++j) {
    int idx = w * 32 + j * 16 + c15;
    asv[j] = a_src[idx];
    adv[j] = a_dst[idx];
  }
#pragma unroll
  for (int i = 0; i < 4; ++i) {
#pragma unroll
    for (int r = 0; r < 4; ++r) {
      int gm = brow + i * 16 + q * 4 + r;
      float pS = acc[i][0][r] * asv[0] + acc[i][1][r] * asv[1];
      float pD = acc[i][0][r] * adv[0] + acc[i][1][r] * adv[1];
#pragma unroll
      for (int off = 1; off < 16; off <<= 1) {
        pS += __shfl_xor(pS, off);
        pD += __shfl_xor(pD, off);
      }
      if (c15 == 0 && gm < M) {
        as1[(size_t)gm * 8 + w] = pS;
        ad1[(size_t)gm * 8 + w] = pD;
      }
    }
  }

  unsigned short* cst = Cst + w * 2048;
#pragma unroll
  for (int i = 0; i < 4; ++i)
#pragma unroll
    for (int j = 0; j < 2; ++j)
#pragma unroll
      for (int r = 0; r < 4; ++r) {
        int row = i * 16 + q * 4 + r;
        cst[row * 32 + j * 16 + c15] = f2bf(acc[i][j][r]);
      }
#pragma unroll
  for (int t2 = 0; t2 < 4; ++t2) {
    int idx = t2 * 64 + lane;
    int row = idx >> 2, ch = idx & 3;
    u16x8 v = *(const u16x8*)&cst[row * 32 + ch * 8];
    int gm = brow + row;
    if (gm < M)
      *(u16x8*)&h1b[(size_t)gm * 256 + w * 32 + ch * 8] = v;
  }
}

// ---------------- GEMM2 fused: h2b = bf16(out1e @ W2) + as2/ad2 epilogue ----------------
__global__ __launch_bounds__(512) void k_gemm2(
    const unsigned short* __restrict__ Ae,
    const unsigned short* __restrict__ Bth, const unsigned short* __restrict__ Btl,
    const float* __restrict__ a_src, const float* __restrict__ a_dst,
    unsigned short* __restrict__ h2b, float* __restrict__ as2, float* __restrict__ ad2,
    int M)
{
  const int t = threadIdx.x, lane = t & 63, w = t >> 6;
  const int lrow = lane & 15, lkb = lane >> 4;
  const int grow = blockIdx.x * 128 + w * 16;

  f32x4 acc[2];
  acc[0] = (f32x4){0.f, 0.f, 0.f, 0.f};
  acc[1] = (f32x4){0.f, 0.f, 0.f, 0.f};

#pragma unroll
  for (int kt = 0; kt < 4; ++kt) {
    const int k0 = kt * 64;
#pragma unroll
    for (int kk = 0; kk < 2; ++kk) {
      bf16x8 a = *(const bf16x8*)&Ae[(size_t)(grow + lrow) * 256 + k0 + kk * 32 + lkb * 8];
#pragma unroll
      for (int j = 0; j < 2; ++j) {
        size_t g = (size_t)(j * 16 + lrow) * 256 + k0 + kk * 32 + lkb * 8;
        bf16x8 bh = *(const bf16x8*)&Bth[g];
        bf16x8 bl = *(const bf16x8*)&Btl[g];
        acc[j] = __builtin_amdgcn_mfma_f32_16x16x32_bf16(a, bh, acc[j], 0, 0, 0);
        acc[j] = __builtin_amdgcn_mfma_f32_16x16x32_bf16(a, bl, acc[j], 0, 0, 0);
      }
    }
  }

  const int c15 = lane & 15, q = lane >> 4;
  float asv[2] = { a_src[c15], a_src[16 + c15] };
  float adv[2] = { a_dst[c15], a_dst[16 + c15] };
#pragma unroll
  for (int r = 0; r < 4; ++r) {
    int gm = grow + q * 4 + r;
    float pS = acc[0][r] * asv[0] + acc[1][r] * asv[1];
    float pD = acc[0][r] * adv[0] + acc[1][r] * adv[1];
#pragma unroll
    for (int off = 1; off < 16; off <<= 1) {
      pS += __shfl_xor(pS, off);
      pD += __shfl_xor(pD, off);
    }
    if (c15 == 0 && gm < M) { as2[gm] = pS; ad2[gm] = pD; }
    if (gm < M) {
      h2b[(size_t)gm * 32 + c15]      = f2bf(acc[0][r]);
      h2b[(size_t)gm * 32 + 16 + c15] = f2bf(acc[1][r]);
    }
  }
}

// ---------------- CSR build ----------------
__global__ void k_deg(const int* __restrict__ ei, int* __restrict__ deg, int E, int etot)
{
  int e = blockIdx.x * blockDim.x + threadIdx.x;
  if (e >= etot) return;
  int dst = (e < E) ? ei[E + e] : (e - E);
  atomicAdd(&deg[dst], 1);
}

__global__ void k_scan1(const int* __restrict__ deg, int* __restrict__ rowptr,
                        int* __restrict__ bsums, int n)
{
  __shared__ int sm[2][1024];
  int t = threadIdx.x, b = blockIdx.x;
  int i = b * 1024 + t;
  int v = (i < n) ? deg[i] : 0;
  sm[0][t] = v;
  __syncthreads();
  int pb = 0;
  for (int off = 1; off < 1024; off <<= 1) {
    int x = sm[pb][t];
    if (t >= off) x += sm[pb][t - off];
    sm[pb ^ 1][t] = x;
    pb ^= 1;
    __syncthreads();
  }
  if (i < n) rowptr[i] = sm[pb][t] - v;
  if (t == 1023) bsums[b] = sm[pb][1023];
}

// scan2+scan3 fused: each thread sums bsums[k < myblock] (nblk <= 64)
__global__ void k_scan23(int* __restrict__ rowptr, const int* __restrict__ bsums,
                         int n, int etot)
{
  int i = blockIdx.x * blockDim.x + threadIdx.x;
  if (i > n) return;
  int b = i >> 10;
  int pre = 0;
  for (int k = 0; k < b; ++k) pre += bsums[k];
  if (i < n) rowptr[i] += pre;
  if (i == 0) rowptr[n] = etot;
}

__global__ void k_fill(const int* __restrict__ ei, const int* __restrict__ rowptr,
                       int* __restrict__ fillc, int* __restrict__ csrsrc, int E, int etot)
{
  int e = blockIdx.x * blockDim.x + threadIdx.x;
  if (e >= etot) return;
  int src, dst;
  if (e < E) { src = ei[e]; dst = ei[E + e]; }
  else { src = dst = e - E; }
  int pos = rowptr[dst] + atomicAdd(&fillc[dst], 1);
  csrsrc[pos] = src;
}

// ---------------- layer-1 aggregation: wave per node, SINGLE PASS ----------------
// Accumulate unnormalized exp-weighted sum + per-head denominator; scale at end.
__global__ __launch_bounds__(256) void k_agg1(const unsigned short* __restrict__ h1b,
    const float* __restrict__ as1, const float* __restrict__ ad1,
    const int* __restrict__ rowptr, const int* __restrict__ csrsrc,
    const float* __restrict__ b1, unsigned short* __restrict__ out1e, int n)
{
  __shared__ float alds[4][64][8];
  __shared__ int   slds[4][64];

  int ns = threadIdx.x >> 6;
  int node = blockIdx.x * 4 + ns;
  if (node >= n) return;
  int lane = threadIdx.x & 63;
  int r0 = rowptr[node];
  int deg = rowptr[node + 1] - r0;

  int h = lane & 7;          // head for fill phase
  int slot = lane >> 3;      // edge slot for fill phase
  float adv = ad1[node * 8 + h];

  int hh = lane >> 3;        // head owning this lane's 4 output cols
  float s = 0.f;             // Σ ex for head h (this lane's slot subset)
  float4 acc = make_float4(0.f, 0.f, 0.f, 0.f);

  for (int c0 = 0; c0 < deg; c0 += 64) {
    // fill: 64 edges x 8 heads of unnormalized exp + src indices
#pragma unroll
    for (int r = 0; r < 8; ++r) {
      int kl = r * 8 + slot;
      int k = c0 + kl;
      if (k < deg) {
        int src = csrsrc[r0 + k];
        float e = fminf(lrelu(as1[src * 8 + h] + adv), 60.f);
        float ex = __expf(e);
        s += ex;
        alds[ns][kl][h] = ex;
        if (h == 0) slds[ns][kl] = src;
      }
    }
    // gather: coalesced ushort4 rows, weighted by unnormalized ex
    int clen = (deg - c0 < 64) ? (deg - c0) : 64;
#pragma unroll 4
    for (int j = 0; j < clen; ++j) {
      float a = alds[ns][j][hh];
      int src = slds[ns][j];
      ushort4 hv = *(const ushort4*)&h1b[(size_t)src * 256 + lane * 4];
      acc.x = fmaf(a, bf2f(hv.x), acc.x);
      acc.y = fmaf(a, bf2f(hv.y), acc.y);
      acc.z = fmaf(a, bf2f(hv.z), acc.z);
      acc.w = fmaf(a, bf2f(hv.w), acc.w);
    }
  }
  // reduce s across slots (lane bits 3,4,5): lane -> Σ ex for head h
#pragma unroll
  for (int off = 8; off < 64; off <<= 1) s += __shfl_xor(s, off);
  // lane needs denominator of head hh; lanes 0..7 hold heads 0..7
  float sh = __shfl(s, hh);
  float inv = 1.f / (sh + 1e-16f);

  float4 bv = *(const float4*)&b1[lane * 4];
  float ox = acc.x * inv + bv.x, oy = acc.y * inv + bv.y;
  float oz = acc.z * inv + bv.z, ow = acc.w * inv + bv.w;
  ushort4 ob;
  ob.x = f2bf(ox > 0.f ? ox : expm1f(ox));
  ob.y = f2bf(oy > 0.f ? oy : expm1f(oy));
  ob.z = f2bf(oz > 0.f ? oz : expm1f(oz));
  ob.w = f2bf(ow > 0.f ? ow : expm1f(ow));
  *(ushort4*)&out1e[(size_t)node * 256 + lane * 4] = ob;
}

// ---------------- layer-2 aggregation: 8 lanes/edge, SINGLE PASS ----------------
__global__ __launch_bounds__(256) void k_agg2(const unsigned short* __restrict__ h2b,
    const float* __restrict__ as2, const float* __restrict__ ad2,
    const int* __restrict__ rowptr, const int* __restrict__ csrsrc,
    const float* __restrict__ b2, float* __restrict__ out, int n)
{
  const int wid = threadIdx.x >> 6;
  const int lane = threadIdx.x & 63;
  const int node = blockIdx.x * 4 + wid;
  if (node >= n) return;

  const int r0 = rowptr[node];
  const int deg = rowptr[node + 1] - r0;
  const float adv = ad2[node];

  const int c4 = lane & 7;
  const int es = lane >> 3;
  float s = 0.f;
  float ax = 0.f, ay = 0.f, az = 0.f, aw = 0.f;

  const int dfull = deg & ~7;
#pragma unroll 2
  for (int c0 = 0; c0 < dfull; c0 += 8) {
    int src = csrsrc[r0 + c0 + es];
    float e = fminf(lrelu(as2[src] + adv), 60.f);
    float ex = __expf(e);
    s += ex;
    ushort4 hv = *(const ushort4*)&h2b[(size_t)src * 32 + c4 * 4];
    ax = fmaf(ex, bf2f(hv.x), ax);
    ay = fmaf(ex, bf2f(hv.y), ay);
    az = fmaf(ex, bf2f(hv.z), az);
    aw = fmaf(ex, bf2f(hv.w), aw);
  }
  if (dfull + es < deg) {
    int src = csrsrc[r0 + dfull + es];
    float e = fminf(lrelu(as2[src] + adv), 60.f);
    float ex = __expf(e);
    s += ex;
    ushort4 hv = *(const ushort4*)&h2b[(size_t)src * 32 + c4 * 4];
    ax = fmaf(ex, bf2f(hv.x), ax);
    ay = fmaf(ex, bf2f(hv.y), ay);
    az = fmaf(ex, bf2f(hv.z), az);
    aw = fmaf(ex, bf2f(hv.w), aw);
  }
  // reduce across edge slots (each edge lives in exactly one es slot)
#pragma unroll
  for (int off = 8; off < 64; off <<= 1) {
    s  += __shfl_xor(s, off);
    ax += __shfl_xor(ax, off);
    ay += __shfl_xor(ay, off);
    az += __shfl_xor(az, off);
    aw += __shfl_xor(aw, off);
  }
  if (es == 0) {
    float inv = 1.f / (s + 1e-16f);
    float4 o;
    o.x = ax * inv + b2[c4 * 4 + 0];
    o.y = ay * inv + b2[c4 * 4 + 1];
    o.z = az * inv + b2[c4 * 4 + 2];
    o.w = aw * inv + b2[c4 * 4 + 3];
    *(float4*)&out[(size_t)node * 32 + c4 * 4] = o;
  }
}

// ---------------- host launch ----------------
extern "C" void kernel_launch(void* const* d_in, const int* in_sizes, int n_in,
                              void* d_out, int out_size, void* d_ws, size_t ws_size,
                              hipStream_t stream)
{
  const float* x      = (const float*)d_in[0];
  const int*   ei     = (const int*)d_in[1];
  const float* W1     = (const float*)d_in[3];
  const float* a_src1 = (const float*)d_in[4];
  const float* a_dst1 = (const float*)d_in[5];
  const float* b1     = (const float*)d_in[6];
  const float* W2     = (const float*)d_in[7];
  const float* a_src2 = (const float*)d_in[8];
  const float* a_dst2 = (const float*)d_in[9];
  const float* b2     = (const float*)d_in[10];
  float* out = (float*)d_out;

  const int n = in_sizes[0] / 256;            // 50000
  const int E = in_sizes[2];                  // 800000
  const int etot = E + n;
  const int Mpad = ((n + 255) / 256) * 256;   // 50176

  // workspace carve
  unsigned short* h1b   = (unsigned short*)d_ws;           // [n][256] bf16 node-major
  unsigned short* out1e = h1b + (size_t)n * 256;           // [Mpad][256] bf16
  unsigned short* h2b   = out1e + (size_t)Mpad * 256;      // n*32 bf16
  float* as1v = (float*)(h2b + (size_t)n * 32);            // [n][8]
  float* ad1v = as1v + (size_t)n * 8;                      // [n][8]
  float* as2v = ad1v + (size_t)n * 8;                      // n
  float* ad2v = as2v + n;                                  // n
  int* rowptr = (int*)(ad2v + n);                          // n+1
  int* degc   = rowptr + (n + 1);                          // n
  int* fillc  = degc + n;                                  // n
  int* csrsrc = fillc + n;                                 // etot
  int* bsums  = csrsrc + etot;                             // <=64
  unsigned short* wth  = (unsigned short*)(bsums + 64);    // 65536
  unsigned short* wtl  = wth + 65536;                      // 65536
  unsigned short* w2th = wtl + 65536;                      // 8192
  unsigned short* w2tl = w2th + 8192;                      // 8192

  // prep: weight splits + zero degc/fillc (2n ints)
  k_prep<<<288, 256, 0, stream>>>(W1, W2, wth, wtl, w2th, w2tl, degc, 2 * n);

  // h1b/as1/ad1 = gemm1(x, W1) fused
  k_gemm1<<<Mpad / 64, 512, 0, stream>>>(x, wth, wtl, a_src1, a_dst1,
                                         h1b, as1v, ad1v, n);

  // CSR build
  int eb = (etot + 255) / 256;
  k_deg<<<eb, 256, 0, stream>>>(ei, degc, E, etot);
  int nblk = (n + 1023) / 1024;
  k_scan1<<<nblk, 1024, 0, stream>>>(degc, rowptr, bsums, n);
  k_scan23<<<(n + 256) / 256, 256, 0, stream>>>(rowptr, bsums, n, etot);
  k_fill<<<eb, 256, 0, stream>>>(ei, rowptr, fillc, csrsrc, E, etot);

  // layer-1 attention (wave per node, all heads, single pass)
  int nb4 = (n + 3) / 4;
  k_agg1<<<nb4, 256, 0, stream>>>(h1b, as1v, ad1v, rowptr, csrsrc, b1, out1e, n);

  // h2b/as2/ad2 = gemm2(out1e, W2) fused
  k_gemm2<<<Mpad / 128, 512, 0, stream>>>(out1e, w2th, w2tl, a_src2, a_dst2,
                                          h2b, as2v, ad2v, n);

  // layer-2 attention -> output
  k_agg2<<<nb4, 256, 0, stream>>>(h2b, as2v, ad2v, rowptr, csrsrc, b2, out, n);
}

// Round 11
// 251.432 us; speedup vs baseline: 1.6256x; 1.0321x over previous
//
#include <hip/hip_runtime.h>
#include <math.h>

typedef __attribute__((ext_vector_type(8))) short bf16x8;
typedef __attribute__((ext_vector_type(8))) unsigned short u16x8;
typedef __attribute__((ext_vector_type(4))) float f32x4;

__device__ __forceinline__ float lrelu(float x) { return x > 0.f ? x : 0.2f * x; }

__device__ __forceinline__ unsigned short f2bf(float f) {
  unsigned int u = __float_as_uint(f);
  unsigned int r = (u + 0x7FFFu + ((u >> 16) & 1u)) >> 16;   // RNE
  return (unsigned short)r;
}
__device__ __forceinline__ float bf2f(unsigned short h) {
  return __uint_as_float(((unsigned int)h) << 16);
}

// swizzled LDS offset (in shorts) for [rows][64]bf16 tile: 16B chunk c16 of row
__device__ __forceinline__ int swz(int row, int c16) {
  return (row * 8 + (c16 ^ (row & 7))) * 8;
}

// ---------------- prep: W1/W2 split+transpose + zero degree/fill counters ----------------
__global__ __launch_bounds__(256) void k_prep(const float* __restrict__ W1,
    const float* __restrict__ W2,
    unsigned short* __restrict__ Wth, unsigned short* __restrict__ Wtl,
    unsigned short* __restrict__ W2th, unsigned short* __restrict__ W2tl,
    int* __restrict__ zeros, int nz)
{
  int bid = blockIdx.x, t = threadIdx.x;
  if (bid < 256) {
    float v = W1[t * 256 + bid];
    unsigned short h = f2bf(v);
    Wth[bid * 256 + t] = h;
    Wtl[bid * 256 + t] = f2bf(v - bf2f(h));
  } else {
    int nn = bid - 256;
    float v = W2[t * 32 + nn];
    unsigned short h = f2bf(v);
    W2th[nn * 256 + t] = h;
    W2tl[nn * 256 + t] = f2bf(v - bf2f(h));
  }
  for (int i = bid * 256 + t; i < nz; i += gridDim.x * 256) zeros[i] = 0;
}

// ---------------- GEMM1: BM=64, wave-per-head, 16KB LDS (4 blocks/CU), fused deg count ----------------
__global__ __launch_bounds__(512, 4) void k_gemm1(
    const float* __restrict__ X,
    const unsigned short* __restrict__ Bth, const unsigned short* __restrict__ Btl,
    const float* __restrict__ a_src, const float* __restrict__ a_dst,
    unsigned short* __restrict__ h1b, float* __restrict__ as1, float* __restrict__ ad1,
    int M,
    const int* __restrict__ ei, int* __restrict__ degc, int E, int etot)
{
  __shared__ __align__(16) unsigned short Ah[64 * 64];   // 8KB
  __shared__ __align__(16) unsigned short Al[64 * 64];   // 8KB
  const int t = threadIdx.x;
  const int lane = t & 63;
  const int w = t >> 6;               // wave = head
  const int lrow = lane & 15, lkb = lane >> 4;
  const int brow = blockIdx.x * 64;

  // folded k_deg: grid-stride atomic histogram (independent; overlaps GEMM)
  for (int e = blockIdx.x * 512 + t; e < etot; e += gridDim.x * 512) {
    int dst = (e < E) ? ei[E + e] : (e - E);
    atomicAdd(&degc[dst], 1);
  }

  f32x4 acc[4][2];
#pragma unroll
  for (int i = 0; i < 4; ++i)
#pragma unroll
    for (int j = 0; j < 2; ++j) acc[i][j] = (f32x4){0.f, 0.f, 0.f, 0.f};

  float4 pref[2];
#pragma unroll
  for (int r = 0; r < 2; ++r) {
    int id = r * 512 + t, m = id >> 4, cq = id & 15, gm = brow + m;
    pref[r] = (gm < M) ? *(const float4*)&X[(size_t)gm * 256 + cq * 4]
                       : make_float4(0.f, 0.f, 0.f, 0.f);
  }

  for (int kt = 0; kt < 4; ++kt) {
    const int k0 = kt * 64;
#pragma unroll
    for (int r = 0; r < 2; ++r) {
      int id = r * 512 + t, m = id >> 4, cq = id & 15;
      float4 v = pref[r];
      unsigned short h0 = f2bf(v.x), h1 = f2bf(v.y), h2 = f2bf(v.z), h3 = f2bf(v.w);
      unsigned short l0 = f2bf(v.x - bf2f(h0)), l1 = f2bf(v.y - bf2f(h1));
      unsigned short l2 = f2bf(v.z - bf2f(h2)), l3 = f2bf(v.w - bf2f(h3));
      int off = swz(m, cq >> 1) + (cq & 1) * 4;
      *(uint2*)&Ah[off] = make_uint2((unsigned)h0 | ((unsigned)h1 << 16),
                                     (unsigned)h2 | ((unsigned)h3 << 16));
      *(uint2*)&Al[off] = make_uint2((unsigned)l0 | ((unsigned)l1 << 16),
                                     (unsigned)l2 | ((unsigned)l3 << 16));
    }
    if (kt < 3) {
#pragma unroll
      for (int r = 0; r < 2; ++r) {
        int id = r * 512 + t, m = id >> 4, cq = id & 15, gm = brow + m;
        pref[r] = (gm < M) ? *(const float4*)&X[(size_t)gm * 256 + k0 + 64 + cq * 4]
                           : make_float4(0.f, 0.f, 0.f, 0.f);
      }
    }
    __syncthreads();
#pragma unroll
    for (int kk = 0; kk < 2; ++kk) {
      bf16x8 bh[2], bl[2];
#pragma unroll
      for (int j = 0; j < 2; ++j) {
        size_t g = (size_t)(w * 32 + j * 16 + lrow) * 256 + k0 + kk * 32 + lkb * 8;
        bh[j] = *(const bf16x8*)&Bth[g];
        bl[j] = *(const bf16x8*)&Btl[g];
      }
#pragma unroll
      for (int i = 0; i < 4; ++i) {
        int row = i * 16 + lrow;
        int lo = swz(row, kk * 4 + lkb);
        bf16x8 ah = *(const bf16x8*)&Ah[lo];
        bf16x8 al = *(const bf16x8*)&Al[lo];
#pragma unroll
        for (int j = 0; j < 2; ++j) {
          acc[i][j] = __builtin_amdgcn_mfma_f32_16x16x32_bf16(ah, bh[j], acc[i][j], 0, 0, 0);
          acc[i][j] = __builtin_amdgcn_mfma_f32_16x16x32_bf16(ah, bl[j], acc[i][j], 0, 0, 0);
          acc[i][j] = __builtin_amdgcn_mfma_f32_16x16x32_bf16(al, bh[j], acc[i][j], 0, 0, 0);
        }
      }
    }
    __syncthreads();
  }

  const int c15 = lane & 15, q = lane >> 4;

  // fused as1/ad1 for head w, interleaved [n][8]
  float asv[2], adv[2];
#pragma unroll
  for (int j = 0; j < 2; ++j) {
    int idx = w * 32 + j * 16 + c15;
    asv[j] = a_src[idx];
    adv[j] = a_dst[idx];
  }
#pragma unroll
  for (int i = 0; i < 4; ++i) {
#pragma unroll
    for (int r = 0; r < 4; ++r) {
      int gm = brow + i * 16 + q * 4 + r;
      float pS = acc[i][0][r] * asv[0] + acc[i][1][r] * asv[1];
      float pD = acc[i][0][r] * adv[0] + acc[i][1][r] * adv[1];
#pragma unroll
      for (int off = 1; off < 16; off <<= 1) {
        pS += __shfl_xor(pS, off);
        pD += __shfl_xor(pD, off);
      }
      if (c15 == 0 && gm < M) {
        as1[(size_t)gm * 8 + w] = pS;
        ad1[(size_t)gm * 8 + w] = pD;
      }
    }
  }

  // C store via per-wave LDS transpose reusing Ah/Al (wave-private 2KB), 2 passes of 16 cols
  unsigned short* cst = (w < 4) ? (Ah + w * 1024) : (Al + (w - 4) * 1024);
#pragma unroll
  for (int jh = 0; jh < 2; ++jh) {
#pragma unroll
    for (int i = 0; i < 4; ++i)
#pragma unroll
      for (int r = 0; r < 4; ++r) {
        int row = i * 16 + q * 4 + r;
        cst[row * 16 + c15] = f2bf(acc[i][jh][r]);
      }
    // same-wave LDS ops are in-order: reads below see this pass's writes,
    // and next pass's writes can't pass these reads
#pragma unroll
    for (int t2 = 0; t2 < 2; ++t2) {
      int idx = t2 * 64 + lane;
      int row = idx >> 1, ch = idx & 1;
      u16x8 v = *(const u16x8*)&cst[row * 16 + ch * 8];
      int gm = brow + row;
      if (gm < M)
        *(u16x8*)&h1b[(size_t)gm * 256 + w * 32 + jh * 16 + ch * 8] = v;
    }
  }
}

// ---------------- GEMM2 fused: h2b = bf16(out1e @ W2) + as2/ad2 epilogue ----------------
__global__ __launch_bounds__(512) void k_gemm2(
    const unsigned short* __restrict__ Ae,
    const unsigned short* __restrict__ Bth, const unsigned short* __restrict__ Btl,
    const float* __restrict__ a_src, const float* __restrict__ a_dst,
    unsigned short* __restrict__ h2b, float* __restrict__ as2, float* __restrict__ ad2,
    int M)
{
  const int t = threadIdx.x, lane = t & 63, w = t >> 6;
  const int lrow = lane & 15, lkb = lane >> 4;
  const int grow = blockIdx.x * 128 + w * 16;

  f32x4 acc[2];
  acc[0] = (f32x4){0.f, 0.f, 0.f, 0.f};
  acc[1] = (f32x4){0.f, 0.f, 0.f, 0.f};

#pragma unroll
  for (int kt = 0; kt < 4; ++kt) {
    const int k0 = kt * 64;
#pragma unroll
    for (int kk = 0; kk < 2; ++kk) {
      bf16x8 a = *(const bf16x8*)&Ae[(size_t)(grow + lrow) * 256 + k0 + kk * 32 + lkb * 8];
#pragma unroll
      for (int j = 0; j < 2; ++j) {
        size_t g = (size_t)(j * 16 + lrow) * 256 + k0 + kk * 32 + lkb * 8;
        bf16x8 bh = *(const bf16x8*)&Bth[g];
        bf16x8 bl = *(const bf16x8*)&Btl[g];
        acc[j] = __builtin_amdgcn_mfma_f32_16x16x32_bf16(a, bh, acc[j], 0, 0, 0);
        acc[j] = __builtin_amdgcn_mfma_f32_16x16x32_bf16(a, bl, acc[j], 0, 0, 0);
      }
    }
  }

  const int c15 = lane & 15, q = lane >> 4;
  float asv[2] = { a_src[c15], a_src[16 + c15] };
  float adv[2] = { a_dst[c15], a_dst[16 + c15] };
#pragma unroll
  for (int r = 0; r < 4; ++r) {
    int gm = grow + q * 4 + r;
    float pS = acc[0][r] * asv[0] + acc[1][r] * asv[1];
    float pD = acc[0][r] * adv[0] + acc[1][r] * adv[1];
#pragma unroll
    for (int off = 1; off < 16; off <<= 1) {
      pS += __shfl_xor(pS, off);
      pD += __shfl_xor(pD, off);
    }
    if (c15 == 0 && gm < M) { as2[gm] = pS; ad2[gm] = pD; }
    if (gm < M) {
      h2b[(size_t)gm * 32 + c15]      = f2bf(acc[0][r]);
      h2b[(size_t)gm * 32 + 16 + c15] = f2bf(acc[1][r]);
    }
  }
}

// ---------------- CSR build ----------------
__global__ void k_scan1(const int* __restrict__ deg, int* __restrict__ rowptr,
                        int* __restrict__ bsums, int n)
{
  __shared__ int sm[2][1024];
  int t = threadIdx.x, b = blockIdx.x;
  int i = b * 1024 + t;
  int v = (i < n) ? deg[i] : 0;
  sm[0][t] = v;
  __syncthreads();
  int pb = 0;
  for (int off = 1; off < 1024; off <<= 1) {
    int x = sm[pb][t];
    if (t >= off) x += sm[pb][t - off];
    sm[pb ^ 1][t] = x;
    pb ^= 1;
    __syncthreads();
  }
  if (i < n) rowptr[i] = sm[pb][t] - v;
  if (t == 1023) bsums[b] = sm[pb][1023];
}

__global__ void k_scan23(int* __restrict__ rowptr, const int* __restrict__ bsums,
                         int n, int etot)
{
  int i = blockIdx.x * blockDim.x + threadIdx.x;
  if (i > n) return;
  int b = i >> 10;
  int pre = 0;
  for (int k = 0; k < b; ++k) pre += bsums[k];
  if (i < n) rowptr[i] += pre;
  if (i == 0) rowptr[n] = etot;
}

__global__ void k_fill(const int* __restrict__ ei, const int* __restrict__ rowptr,
                       int* __restrict__ fillc, int* __restrict__ csrsrc, int E, int etot)
{
  int e = blockIdx.x * blockDim.x + threadIdx.x;
  if (e >= etot) return;
  int src, dst;
  if (e < E) { src = ei[e]; dst = ei[E + e]; }
  else { src = dst = e - E; }
  int pos = rowptr[dst] + atomicAdd(&fillc[dst], 1);
  csrsrc[pos] = src;
}

// ---------------- layer-1 aggregation: wave per node, single pass ----------------
__global__ __launch_bounds__(256) void k_agg1(const unsigned short* __restrict__ h1b,
    const float* __restrict__ as1, const float* __restrict__ ad1,
    const int* __restrict__ rowptr, const int* __restrict__ csrsrc,
    const float* __restrict__ b1, unsigned short* __restrict__ out1e, int n)
{
  __shared__ float alds[4][64][8];
  __shared__ int   slds[4][64];

  int ns = threadIdx.x >> 6;
  int node = blockIdx.x * 4 + ns;
  if (node >= n) return;
  int lane = threadIdx.x & 63;
  int r0 = rowptr[node];
  int deg = rowptr[node + 1] - r0;

  int h = lane & 7;
  int slot = lane >> 3;
  float adv = ad1[node * 8 + h];

  int hh = lane >> 3;
  float s = 0.f;
  float4 acc = make_float4(0.f, 0.f, 0.f, 0.f);

  for (int c0 = 0; c0 < deg; c0 += 64) {
#pragma unroll
    for (int r = 0; r < 8; ++r) {
      int kl = r * 8 + slot;
      int k = c0 + kl;
      if (k < deg) {
        int src = csrsrc[r0 + k];
        float e = fminf(lrelu(as1[src * 8 + h] + adv), 60.f);
        float ex = __expf(e);
        s += ex;
        alds[ns][kl][h] = ex;
        if (h == 0) slds[ns][kl] = src;
      }
    }
    int clen = (deg - c0 < 64) ? (deg - c0) : 64;
#pragma unroll 4
    for (int j = 0; j < clen; ++j) {
      float a = alds[ns][j][hh];
      int src = slds[ns][j];
      ushort4 hv = *(const ushort4*)&h1b[(size_t)src * 256 + lane * 4];
      acc.x = fmaf(a, bf2f(hv.x), acc.x);
      acc.y = fmaf(a, bf2f(hv.y), acc.y);
      acc.z = fmaf(a, bf2f(hv.z), acc.z);
      acc.w = fmaf(a, bf2f(hv.w), acc.w);
    }
  }
#pragma unroll
  for (int off = 8; off < 64; off <<= 1) s += __shfl_xor(s, off);
  float sh = __shfl(s, hh);
  float inv = 1.f / (sh + 1e-16f);

  float4 bv = *(const float4*)&b1[lane * 4];
  float ox = acc.x * inv + bv.x, oy = acc.y * inv + bv.y;
  float oz = acc.z * inv + bv.z, ow = acc.w * inv + bv.w;
  ushort4 ob;
  ob.x = f2bf(ox > 0.f ? ox : expm1f(ox));
  ob.y = f2bf(oy > 0.f ? oy : expm1f(oy));
  ob.z = f2bf(oz > 0.f ? oz : expm1f(oz));
  ob.w = f2bf(ow > 0.f ? ow : expm1f(ow));
  *(ushort4*)&out1e[(size_t)node * 256 + lane * 4] = ob;
}

// ---------------- layer-2 aggregation: 8 lanes/edge, single pass ----------------
__global__ __launch_bounds__(256) void k_agg2(const unsigned short* __restrict__ h2b,
    const float* __restrict__ as2, const float* __restrict__ ad2,
    const int* __restrict__ rowptr, const int* __restrict__ csrsrc,
    const float* __restrict__ b2, float* __restrict__ out, int n)
{
  const int wid = threadIdx.x >> 6;
  const int lane = threadIdx.x & 63;
  const int node = blockIdx.x * 4 + wid;
  if (node >= n) return;

  const int r0 = rowptr[node];
  const int deg = rowptr[node + 1] - r0;
  const float adv = ad2[node];

  const int c4 = lane & 7;
  const int es = lane >> 3;
  float s = 0.f;
  float ax = 0.f, ay = 0.f, az = 0.f, aw = 0.f;

  const int dfull = deg & ~7;
#pragma unroll 2
  for (int c0 = 0; c0 < dfull; c0 += 8) {
    int src = csrsrc[r0 + c0 + es];
    float e = fminf(lrelu(as2[src] + adv), 60.f);
    float ex = __expf(e);
    s += ex;
    ushort4 hv = *(const ushort4*)&h2b[(size_t)src * 32 + c4 * 4];
    ax = fmaf(ex, bf2f(hv.x), ax);
    ay = fmaf(ex, bf2f(hv.y), ay);
    az = fmaf(ex, bf2f(hv.z), az);
    aw = fmaf(ex, bf2f(hv.w), aw);
  }
  if (dfull + es < deg) {
    int src = csrsrc[r0 + dfull + es];
    float e = fminf(lrelu(as2[src] + adv), 60.f);
    float ex = __expf(e);
    s += ex;
    ushort4 hv = *(const ushort4*)&h2b[(size_t)src * 32 + c4 * 4];
    ax = fmaf(ex, bf2f(hv.x), ax);
    ay = fmaf(ex, bf2f(hv.y), ay);
    az = fmaf(ex, bf2f(hv.z), az);
    aw = fmaf(ex, bf2f(hv.w), aw);
  }
#pragma unroll
  for (int off = 8; off < 64; off <<= 1) {
    s  += __shfl_xor(s, off);
    ax += __shfl_xor(ax, off);
    ay += __shfl_xor(ay, off);
    az += __shfl_xor(az, off);
    aw += __shfl_xor(aw, off);
  }
  if (es == 0) {
    float inv = 1.f / (s + 1e-16f);
    float4 o;
    o.x = ax * inv + b2[c4 * 4 + 0];
    o.y = ay * inv + b2[c4 * 4 + 1];
    o.z = az * inv + b2[c4 * 4 + 2];
    o.w = aw * inv + b2[c4 * 4 + 3];
    *(float4*)&out[(size_t)node * 32 + c4 * 4] = o;
  }
}

// ---------------- host launch ----------------
extern "C" void kernel_launch(void* const* d_in, const int* in_sizes, int n_in,
                              void* d_out, int out_size, void* d_ws, size_t ws_size,
                              hipStream_t stream)
{
  const float* x      = (const float*)d_in[0];
  const int*   ei     = (const int*)d_in[1];
  const float* W1     = (const float*)d_in[3];
  const float* a_src1 = (const float*)d_in[4];
  const float* a_dst1 = (const float*)d_in[5];
  const float* b1     = (const float*)d_in[6];
  const float* W2     = (const float*)d_in[7];
  const float* a_src2 = (const float*)d_in[8];
  const float* a_dst2 = (const float*)d_in[9];
  const float* b2     = (const float*)d_in[10];
  float* out = (float*)d_out;

  const int n = in_sizes[0] / 256;            // 50000
  const int E = in_sizes[2];                  // 800000
  const int etot = E + n;
  const int Mpad = ((n + 255) / 256) * 256;   // 50176

  // workspace carve
  unsigned short* h1b   = (unsigned short*)d_ws;           // [n][256] bf16 node-major
  unsigned short* out1e = h1b + (size_t)n * 256;           // [Mpad][256] bf16
  unsigned short* h2b   = out1e + (size_t)Mpad * 256;      // n*32 bf16
  float* as1v = (float*)(h2b + (size_t)n * 32);            // [n][8]
  float* ad1v = as1v + (size_t)n * 8;                      // [n][8]
  float* as2v = ad1v + (size_t)n * 8;                      // n
  float* ad2v = as2v + n;                                  // n
  int* rowptr = (int*)(ad2v + n);                          // n+1
  int* degc   = rowptr + (n + 1);                          // n
  int* fillc  = degc + n;                                  // n
  int* csrsrc = fillc + n;                                 // etot
  int* bsums  = csrsrc + etot;                             // <=64
  unsigned short* wth  = (unsigned short*)(bsums + 64);    // 65536
  unsigned short* wtl  = wth + 65536;                      // 65536
  unsigned short* w2th = wtl + 65536;                      // 8192
  unsigned short* w2tl = w2th + 8192;                      // 8192

  // prep: weight splits + zero degc/fillc (2n ints)
  k_prep<<<288, 256, 0, stream>>>(W1, W2, wth, wtl, w2th, w2tl, degc, 2 * n);

  // h1b/as1/ad1 = gemm1(x, W1) fused; also counts degrees (folded k_deg)
  k_gemm1<<<Mpad / 64, 512, 0, stream>>>(x, wth, wtl, a_src1, a_dst1,
                                         h1b, as1v, ad1v, n, ei, degc, E, etot);

  // CSR build
  int nblk = (n + 1023) / 1024;
  k_scan1<<<nblk, 1024, 0, stream>>>(degc, rowptr, bsums, n);
  k_scan23<<<(n + 256) / 256, 256, 0, stream>>>(rowptr, bsums, n, etot);
  int eb = (etot + 255) / 256;
  k_fill<<<eb, 256, 0, stream>>>(ei, rowptr, fillc, csrsrc, E, etot);

  // layer-1 attention (wave per node, all heads, single pass)
  int nb4 = (n + 3) / 4;
  k_agg1<<<nb4, 256, 0, stream>>>(h1b, as1v, ad1v, rowptr, csrsrc, b1, out1e, n);

  // h2b/as2/ad2 = gemm2(out1e, W2) fused
  k_gemm2<<<Mpad / 128, 512, 0, stream>>>(out1e, w2th, w2tl, a_src2, a_dst2,
                                          h2b, as2v, ad2v, n);

  // layer-2 attention -> output
  k_agg2<<<nb4, 256, 0, stream>>>(h2b, as2v, ad2v, rowptr, csrsrc, b2, out, n);
}